// Round 15
// baseline (480.756 us; speedup 1.0000x reference)
//
#include <hip/hip_runtime.h>
#include <math.h>

#define N_NODES 50000
#define N_EDGES 800000
#define ETOT (N_EDGES + N_NODES)
#define G_GRAPHS 128
#define HD 128
#define COND_F 7
#define NFEAT 135
#define LAT 32
#define L_LAYERS 3
#define SLOPE 0.2f
#define MAXDEG 96
#define SC_BLOCKS 64
#define SC_RANGE ((N_NODES + SC_BLOCKS - 1) / SC_BLOCKS)  // 782

typedef __attribute__((ext_vector_type(8))) short bf16x8;
typedef __attribute__((ext_vector_type(4))) float f32x4;

__device__ __forceinline__ float leaky_(float x) { return x > 0.f ? x : SLOPE * x; }

__device__ __forceinline__ unsigned short f2bf_(float f) {
    unsigned int u = __float_as_uint(f);
    u += 0x7FFF + ((u >> 16) & 1);  // round-to-nearest-even
    return (unsigned short)(u >> 16);
}
__device__ __forceinline__ float bf2f_(unsigned short b) {
    return __uint_as_float((unsigned int)b << 16);
}
__device__ __forceinline__ unsigned int pack_bf2_(float lo, float hi) {
    unsigned int ulo = __float_as_uint(lo); ulo += 0x7FFF + ((ulo >> 16) & 1);
    unsigned int uhi = __float_as_uint(hi); uhi += 0x7FFF + ((uhi >> 16) & 1);
    return (ulo >> 16) | (uhi & 0xFFFF0000u);
}

// ---------------- range-owner CSR build (no global atomics) ----------------
// Block b exclusively owns dsts [b*SC_RANGE, ...+SC_RANGE): scans the full dst
// plane (L2-resident, coalesced int4), LDS slot counters, writes only its
// private slot-major region -> no cross-XCD line sharing, writebacks ~payload.
// Self-loops = slot-0 plane (deterministic, coalesced). fill needs no memset.
__global__ __launch_bounds__(1024) void scatter_kernel(const int* __restrict__ ei,
                                                       int* __restrict__ fill,
                                                       int* __restrict__ csr) {
    __shared__ int cnt[SC_RANGE];
    int b = blockIdx.x, t = threadIdx.x;
    int base = b * SC_RANGE;
    int lim = min(SC_RANGE, N_NODES - base);
    for (int j = t; j < lim; j += 1024) {
        cnt[j] = 1;
        csr[base + j] = base + j;  // slot 0 (= 0*N_NODES + d): self-loop
    }
    __syncthreads();
    const int4* d4 = (const int4*)(ei + N_EDGES);
    const int nv = N_EDGES / 4;
    int up = base + lim;
    for (int i = t; i < nv; i += 1024) {
        int4 d = d4[i];
        int idx = i * 4;
        if (d.x >= base && d.x < up) {
            int slot = atomicAdd(&cnt[d.x - base], 1);
            if (slot < MAXDEG) csr[slot * N_NODES + d.x] = ei[idx + 0];
        }
        if (d.y >= base && d.y < up) {
            int slot = atomicAdd(&cnt[d.y - base], 1);
            if (slot < MAXDEG) csr[slot * N_NODES + d.y] = ei[idx + 1];
        }
        if (d.z >= base && d.z < up) {
            int slot = atomicAdd(&cnt[d.z - base], 1);
            if (slot < MAXDEG) csr[slot * N_NODES + d.z] = ei[idx + 2];
        }
        if (d.w >= base && d.w < up) {
            int slot = atomicAdd(&cnt[d.w - base], 1);
            if (slot < MAXDEG) csr[slot * N_NODES + d.w] = ei[idx + 3];
        }
    }
    __syncthreads();
    for (int j = t; j < lim; j += 1024) fill[base + j] = min(cnt[j], MAXDEG);
}

// ---------------- fused weight prep: Wt (bf16 W^T) + Wa (logit matrix) ----
__global__ void prep_kernel(const float* __restrict__ W, const float* __restrict__ a_s,
                            const float* __restrict__ a_d, unsigned short* __restrict__ Wt,
                            unsigned short* __restrict__ Wa) {
    int i = blockIdx.x * blockDim.x + threadIdx.x;
    const int NW = L_LAYERS * 128 * 128;
    if (i < NW) {
        int l = i >> 14, rem = i & 16383, k = rem >> 7, n = rem & 127;
        unsigned int u = __float_as_uint(W[i]);
        u += 0x7FFF + ((u >> 16) & 1);
        Wt[(l << 14) + n * 128 + k] = (unsigned short)(u >> 16);
        return;
    }
    int j = i - NW;
    if (j >= L_LAYERS * 16 * 128) return;
    int l = j >> 11, rem = j & 2047, c = rem >> 7, k = rem & 127;
    float v = 0.f;
    if (c < 8) {
        int h = c >> 1;
        const float* av = (c & 1) ? &a_d[l * 128 + h * 32] : &a_s[l * 128 + h * 32];
        const float* wrow = &W[(l << 14) + k * 128 + h * 32];
#pragma unroll
        for (int d = 0; d < 32; ++d) v = fmaf(wrow[d], av[d], v);
    }
    Wa[j] = f2bf_(v);
}

// ---------------- MFMA GEMM + fused attention logits ----------------
// h_bf = bf16(x @ W); al_s/al_d from an extra MFMA column-tile on wave 0.
// Measured round 11: ~13 us per dispatch (duplicate-launch differencing).
__global__ __launch_bounds__(256) void gemm_mfma_kernel(
    const float* __restrict__ x, const unsigned short* __restrict__ Wt,
    const unsigned short* __restrict__ Wa,
    unsigned short* __restrict__ h_bf, float* __restrict__ al_s,
    float* __restrict__ al_d) {
    __shared__ __align__(16) unsigned short xs[64 * 128];  // bf16, XOR-swizzled rows (256B)
    int t = threadIdx.x;
    int lane = t & 63;
    int w = t >> 6;
    int row0 = blockIdx.x * 64;

    // stage A: thread t -> row t>>2, cols (t&3)*32 .. +31 (fp32 -> bf16)
    {
        int r = t >> 2, c0 = (t & 3) * 32;
        int gr = row0 + r;
        unsigned int upk[16];
        if (gr < N_NODES) {
            const float* src = &x[(size_t)gr * 128 + c0];
#pragma unroll
            for (int i = 0; i < 8; ++i) {
                float4 v = *(const float4*)&src[i * 4];
                upk[i * 2 + 0] = pack_bf2_(v.x, v.y);
                upk[i * 2 + 1] = pack_bf2_(v.z, v.w);
            }
        } else {
#pragma unroll
            for (int i = 0; i < 16; ++i) upk[i] = 0;
        }
        char* base = (char*)xs + r * 256;
#pragma unroll
        for (int i = 0; i < 4; ++i) {
            int cb = c0 * 2 + i * 16;
            int sw = cb ^ ((r & 7) << 4);
            *(uint4*)(base + sw) = make_uint4(upk[i * 4 + 0], upk[i * 4 + 1],
                                              upk[i * 4 + 2], upk[i * 4 + 3]);
        }
    }
    int l15 = lane & 15, g16 = lane >> 4;
    int cn = w * 32;
    bf16x8 bfr[2][4];
#pragma unroll
    for (int ct = 0; ct < 2; ++ct)
#pragma unroll
        for (int ks = 0; ks < 4; ++ks)
            bfr[ct][ks] = *(const bf16x8*)&Wt[(size_t)(cn + ct * 16 + l15) * 128 + ks * 32 + g16 * 8];
    bf16x8 bfrL[4];
    if (w == 0) {
#pragma unroll
        for (int ks = 0; ks < 4; ++ks)
            bfrL[ks] = *(const bf16x8*)&Wa[l15 * 128 + ks * 32 + g16 * 8];
    }
    __syncthreads();

    f32x4 acc[4][2];
    f32x4 accL[4];
#pragma unroll
    for (int rt = 0; rt < 4; ++rt) {
#pragma unroll
        for (int ct = 0; ct < 2; ++ct) acc[rt][ct] = (f32x4){0.f, 0.f, 0.f, 0.f};
        accL[rt] = (f32x4){0.f, 0.f, 0.f, 0.f};
    }

#pragma unroll
    for (int ks = 0; ks < 4; ++ks) {
        bf16x8 af[4];
#pragma unroll
        for (int rt = 0; rt < 4; ++rt) {
            int r = rt * 16 + l15;
            int cb = ks * 64 + g16 * 16;
            af[rt] = *(const bf16x8*)((const char*)xs + r * 256 + (cb ^ ((r & 7) << 4)));
        }
#pragma unroll
        for (int rt = 0; rt < 4; ++rt)
#pragma unroll
            for (int ct = 0; ct < 2; ++ct)
                acc[rt][ct] = __builtin_amdgcn_mfma_f32_16x16x32_bf16(
                    af[rt], bfr[ct][ks], acc[rt][ct], 0, 0, 0);
        if (w == 0) {
#pragma unroll
            for (int rt = 0; rt < 4; ++rt)
                accL[rt] = __builtin_amdgcn_mfma_f32_16x16x32_bf16(
                    af[rt], bfrL[ks], accL[rt], 0, 0, 0);
        }
    }

    __syncthreads();  // all waves done reading xs; reuse it as the output tile

#pragma unroll
    for (int rt = 0; rt < 4; ++rt) {
#pragma unroll
        for (int j = 0; j < 4; ++j) {
            int r = rt * 16 + g16 * 4 + j;
            int sw = (r & 7) << 4;
            char* rowb = (char*)xs + r * 256;
            *(unsigned short*)(rowb + (((cn + l15) * 2) ^ sw)) = f2bf_(acc[rt][0][j]);
            *(unsigned short*)(rowb + (((cn + 16 + l15) * 2) ^ sw)) = f2bf_(acc[rt][1][j]);
        }
    }
    if (w == 0) {
#pragma unroll
        for (int rt = 0; rt < 4; ++rt) {
#pragma unroll
            for (int j = 0; j < 4; ++j) {
                int grow = row0 + rt * 16 + g16 * 4 + j;
                if (l15 < 8 && grow < N_NODES) {
                    float v = accL[rt][j];
                    if (l15 & 1) al_d[grow * 4 + (l15 >> 1)] = v;
                    else al_s[grow * 4 + (l15 >> 1)] = v;
                }
            }
        }
    }
    __syncthreads();
#pragma unroll
    for (int i = 0; i < 4; ++i) {
        int flat = i * 4096 + t * 16;
        int r = flat >> 8;
        int cb = flat & 255;
        uint4 v = *(const uint4*)((const char*)xs + r * 256 + (cb ^ ((r & 7) << 4)));
        int gr = row0 + r;
        if (gr < N_NODES)
            *(uint4*)((char*)&h_bf[(size_t)gr * 128] + cb) = v;
    }
}

// ---------------- per-dst softmax + aggregation (1 wave / node) ----------------
// Byte-identical to round 14 (slot-major csr reads; <=51.7us measured).
__global__ __launch_bounds__(256) void agg_kernel(
    const unsigned short* __restrict__ h_bf, const float* __restrict__ al_s,
    const float* __restrict__ al_d, const int* __restrict__ deg_arr,
    const int* __restrict__ csr, const float* __restrict__ bias,
    float* __restrict__ xout) {
    __shared__ float alph[4][64][4];
    __shared__ int srcs[4][64];
    __shared__ float bounce[4][160];
    int wslot = threadIdx.x >> 6;
    int wv = (blockIdx.x * blockDim.x + threadIdx.x) >> 6;
    int lane = threadIdx.x & 63;
    if (wv >= N_NODES) return;
    int node = wv;
    int deg = deg_arr[node];
    float4 ad = *(const float4*)&al_d[node * 4];

    if (deg <= 64) {
        float e0 = -1e30f, e1 = -1e30f, e2 = -1e30f, e3 = -1e30f;
        int s_l = 0;
        if (lane < deg) {
            s_l = csr[lane * N_NODES + node];
            float4 as = *(const float4*)&al_s[s_l * 4];
            e0 = leaky_(as.x + ad.x);
            e1 = leaky_(as.y + ad.y);
            e2 = leaky_(as.z + ad.z);
            e3 = leaky_(as.w + ad.w);
        }
        float m0 = e0, m1 = e1, m2 = e2, m3 = e3;
#pragma unroll
        for (int off = 1; off < 64; off <<= 1) {
            m0 = fmaxf(m0, __shfl_xor(m0, off));
            m1 = fmaxf(m1, __shfl_xor(m1, off));
            m2 = fmaxf(m2, __shfl_xor(m2, off));
            m3 = fmaxf(m3, __shfl_xor(m3, off));
        }
        float x0 = 0.f, x1 = 0.f, x2 = 0.f, x3 = 0.f;
        if (lane < deg) {
            x0 = __expf(e0 - m0);
            x1 = __expf(e1 - m1);
            x2 = __expf(e2 - m2);
            x3 = __expf(e3 - m3);
        }
        float d0 = x0, d1 = x1, d2 = x2, d3 = x3;
#pragma unroll
        for (int off = 1; off < 64; off <<= 1) {
            d0 += __shfl_xor(d0, off);
            d1 += __shfl_xor(d1, off);
            d2 += __shfl_xor(d2, off);
            d3 += __shfl_xor(d3, off);
        }
        float i0 = 1.f / (d0 + 1e-16f), i1 = 1.f / (d1 + 1e-16f);
        float i2 = 1.f / (d2 + 1e-16f), i3 = 1.f / (d3 + 1e-16f);

        *(float4*)&alph[wslot][lane][0] =
            make_float4(x0 * i0, x1 * i1, x2 * i2, x3 * i3);
        srcs[wslot][lane] = s_l;

        int grp = lane >> 4, li = lane & 15;
        int hq = li >> 2;  // head of features 8*li .. 8*li+7
        float facc[8];
#pragma unroll
        for (int k = 0; k < 8; ++k) facc[k] = 0.f;
        int degr = (deg + 3) & ~3;  // LDS is zero-padded: branch-free chunks
        int j0 = 0;
        for (; j0 + 8 <= degr; j0 += 8) {
            int eA = j0 + grp, eB = j0 + 4 + grp;
            int sA = srcs[wslot][eA];
            int sB = srcs[wslot][eB];
            float aA = alph[wslot][eA][hq];
            float aB = alph[wslot][eB][hq];
            uint4 vA = *(const uint4*)&h_bf[(size_t)sA * 128 + li * 8];
            uint4 vB = *(const uint4*)&h_bf[(size_t)sB * 128 + li * 8];
            facc[0] = fmaf(aA, __uint_as_float(vA.x << 16), facc[0]);
            facc[1] = fmaf(aA, __uint_as_float(vA.x & 0xFFFF0000u), facc[1]);
            facc[2] = fmaf(aA, __uint_as_float(vA.y << 16), facc[2]);
            facc[3] = fmaf(aA, __uint_as_float(vA.y & 0xFFFF0000u), facc[3]);
            facc[4] = fmaf(aA, __uint_as_float(vA.z << 16), facc[4]);
            facc[5] = fmaf(aA, __uint_as_float(vA.z & 0xFFFF0000u), facc[5]);
            facc[6] = fmaf(aA, __uint_as_float(vA.w << 16), facc[6]);
            facc[7] = fmaf(aA, __uint_as_float(vA.w & 0xFFFF0000u), facc[7]);
            facc[0] = fmaf(aB, __uint_as_float(vB.x << 16), facc[0]);
            facc[1] = fmaf(aB, __uint_as_float(vB.x & 0xFFFF0000u), facc[1]);
            facc[2] = fmaf(aB, __uint_as_float(vB.y << 16), facc[2]);
            facc[3] = fmaf(aB, __uint_as_float(vB.y & 0xFFFF0000u), facc[3]);
            facc[4] = fmaf(aB, __uint_as_float(vB.z << 16), facc[4]);
            facc[5] = fmaf(aB, __uint_as_float(vB.z & 0xFFFF0000u), facc[5]);
            facc[6] = fmaf(aB, __uint_as_float(vB.w << 16), facc[6]);
            facc[7] = fmaf(aB, __uint_as_float(vB.w & 0xFFFF0000u), facc[7]);
        }
        if (j0 < degr) {
            int e = j0 + grp;
            int s = srcs[wslot][e];
            float a = alph[wslot][e][hq];
            uint4 v = *(const uint4*)&h_bf[(size_t)s * 128 + li * 8];
            facc[0] = fmaf(a, __uint_as_float(v.x << 16), facc[0]);
            facc[1] = fmaf(a, __uint_as_float(v.x & 0xFFFF0000u), facc[1]);
            facc[2] = fmaf(a, __uint_as_float(v.y << 16), facc[2]);
            facc[3] = fmaf(a, __uint_as_float(v.y & 0xFFFF0000u), facc[3]);
            facc[4] = fmaf(a, __uint_as_float(v.z << 16), facc[4]);
            facc[5] = fmaf(a, __uint_as_float(v.z & 0xFFFF0000u), facc[5]);
            facc[6] = fmaf(a, __uint_as_float(v.w << 16), facc[6]);
            facc[7] = fmaf(a, __uint_as_float(v.w & 0xFFFF0000u), facc[7]);
        }
#pragma unroll
        for (int k = 0; k < 8; ++k) {
            facc[k] += __shfl_xor(facc[k], 16);
            facc[k] += __shfl_xor(facc[k], 32);
        }
        if (grp == 0) {
            // feature li*8+k stored at [k*17+li]: 16 distinct banks per k
#pragma unroll
            for (int k = 0; k < 8; ++k) bounce[wslot][k * 17 + li] = facc[k];
        }
        // single-wave LDS write->read: ordered via lgkmcnt, no barrier needed
        int fA = lane, fB = lane + 64;
        float o0 = bounce[wslot][(fA & 7) * 17 + (fA >> 3)];
        float o1 = bounce[wslot][(fB & 7) * 17 + (fB >> 3)];
        xout[node * 128 + fA] = leaky_(o0 + bias[fA]);
        xout[node * 128 + fB] = leaky_(o1 + bias[fB]);
    } else {
        // generic fallback (64 < deg <= MAXDEG) — rare for this input
        int f0 = lane, f1 = lane + 64;
        int hA = lane >> 5;
        float acc0 = 0.f, acc1 = 0.f;
        float m0 = -1e30f, m1 = -1e30f, m2 = -1e30f, m3 = -1e30f;
        for (int e = lane; e < deg; e += 64) {
            int s = csr[e * N_NODES + node];
            float4 as = *(const float4*)&al_s[s * 4];
            m0 = fmaxf(m0, leaky_(as.x + ad.x));
            m1 = fmaxf(m1, leaky_(as.y + ad.y));
            m2 = fmaxf(m2, leaky_(as.z + ad.z));
            m3 = fmaxf(m3, leaky_(as.w + ad.w));
        }
#pragma unroll
        for (int off = 1; off < 64; off <<= 1) {
            m0 = fmaxf(m0, __shfl_xor(m0, off));
            m1 = fmaxf(m1, __shfl_xor(m1, off));
            m2 = fmaxf(m2, __shfl_xor(m2, off));
            m3 = fmaxf(m3, __shfl_xor(m3, off));
        }
        float d0 = 0.f, d1 = 0.f, d2 = 0.f, d3 = 0.f;
        for (int e = lane; e < deg; e += 64) {
            int s = csr[e * N_NODES + node];
            float4 as = *(const float4*)&al_s[s * 4];
            d0 += __expf(leaky_(as.x + ad.x) - m0);
            d1 += __expf(leaky_(as.y + ad.y) - m1);
            d2 += __expf(leaky_(as.z + ad.z) - m2);
            d3 += __expf(leaky_(as.w + ad.w) - m3);
        }
#pragma unroll
        for (int off = 1; off < 64; off <<= 1) {
            d0 += __shfl_xor(d0, off);
            d1 += __shfl_xor(d1, off);
            d2 += __shfl_xor(d2, off);
            d3 += __shfl_xor(d3, off);
        }
        float i0 = 1.f / (d0 + 1e-16f), i1 = 1.f / (d1 + 1e-16f);
        float i2 = 1.f / (d2 + 1e-16f), i3 = 1.f / (d3 + 1e-16f);
        float adA = hA ? ad.y : ad.x, adB = hA ? ad.w : ad.z;
        float mA = hA ? m1 : m0, mB = hA ? m3 : m2;
        float iA = hA ? i1 : i0, iB = hA ? i3 : i2;
        for (int e = 0; e < deg; ++e) {
            int s = csr[e * N_NODES + node];
            float asA = al_s[s * 4 + hA];
            float asB = al_s[s * 4 + 2 + hA];
            float aA = __expf(leaky_(asA + adA) - mA) * iA;
            float aB = __expf(leaky_(asB + adB) - mB) * iB;
            acc0 = fmaf(aA, bf2f_(h_bf[s * 128 + f0]), acc0);
            acc1 = fmaf(aB, bf2f_(h_bf[s * 128 + f1]), acc1);
        }
        xout[node * 128 + f0] = leaky_(acc0 + bias[f0]);
        xout[node * 128 + f1] = leaky_(acc1 + bias[f1]);
    }
}

// ---------------- pooling (batch is sorted) ----------------
#define POOL_CHUNK 128
__global__ __launch_bounds__(256) void pool_kernel(const float* __restrict__ x,
                                                   const int* __restrict__ batch,
                                                   float* __restrict__ pooled) {
    int wv = (blockIdx.x * blockDim.x + threadIdx.x) >> 6;
    int lane = threadIdx.x & 63;
    int n0 = wv * POOL_CHUNK;
    if (n0 >= N_NODES) return;
    int n1 = min(n0 + POOL_CHUNK, N_NODES);
    float a0 = 0.f, a1 = 0.f;
    int gcur = batch[n0];
    for (int n = n0; n < n1; ++n) {
        int g = batch[n];
        if (g != gcur) {
            atomicAdd(&pooled[gcur * 128 + lane], a0);
            atomicAdd(&pooled[gcur * 128 + 64 + lane], a1);
            a0 = a1 = 0.f;
            gcur = g;
        }
        a0 += x[n * 128 + lane];
        a1 += x[n * 128 + 64 + lane];
    }
    atomicAdd(&pooled[gcur * 128 + lane], a0);
    atomicAdd(&pooled[gcur * 128 + 64 + lane], a1);
}

// ---------------- BatchNorm + FC (single block; tiny) ----------------
__global__ __launch_bounds__(256) void bnfc_kernel(
    const float* __restrict__ pooled, const float* __restrict__ cond,
    const float* __restrict__ gamma, const float* __restrict__ beta,
    const float* __restrict__ fcw, const float* __restrict__ fcb,
    float* __restrict__ out) {
    __shared__ float Y[G_GRAPHS * NFEAT];
    __shared__ float scale[NFEAT], shift[NFEAT];
    int t = threadIdx.x;
    for (int idx = t; idx < G_GRAPHS * NFEAT; idx += 256) {
        int g = idx / NFEAT, f = idx % NFEAT;
        Y[idx] = (f < HD) ? pooled[g * HD + f] : cond[g * COND_F + (f - HD)];
    }
    __syncthreads();
    if (t < NFEAT) {
        float s = 0.f;
        for (int g = 0; g < G_GRAPHS; ++g) s += Y[g * NFEAT + t];
        float mean = s * (1.f / G_GRAPHS);
        float v = 0.f;
        for (int g = 0; g < G_GRAPHS; ++g) {
            float dd = Y[g * NFEAT + t] - mean;
            v += dd * dd;
        }
        v *= (1.f / G_GRAPHS);
        float inv = rsqrtf(v + 1e-5f);
        float sc = gamma[t] * inv;
        scale[t] = sc;
        shift[t] = beta[t] - mean * sc;
    }
    __syncthreads();
    for (int idx = t; idx < G_GRAPHS * NFEAT; idx += 256) {
        int f = idx % NFEAT;
        Y[idx] = Y[idx] * scale[f] + shift[f];
    }
    __syncthreads();
    for (int idx = t; idx < G_GRAPHS * LAT; idx += 256) {
        int g = idx >> 5, j = idx & 31;
        float acc = fcb[j];
        for (int f = 0; f < NFEAT; ++f) acc = fmaf(Y[g * NFEAT + f], fcw[f * LAT + j], acc);
        out[idx] = acc;
    }
}

extern "C" void kernel_launch(void* const* d_in, const int* in_sizes, int n_in,
                              void* d_out, int out_size, void* d_ws, size_t ws_size,
                              hipStream_t stream) {
    const float* x_in = (const float*)d_in[0];
    const float* cond = (const float*)d_in[1];
    const float* W = (const float*)d_in[2];
    const float* a_src = (const float*)d_in[3];
    const float* a_dst = (const float*)d_in[4];
    const float* conv_bias = (const float*)d_in[5];
    const float* bn_gamma = (const float*)d_in[6];
    const float* bn_beta = (const float*)d_in[7];
    const float* fc_w = (const float*)d_in[8];
    const float* fc_b = (const float*)d_in[9];
    const int* edge_index = (const int*)d_in[10];
    const int* batch = (const int*)d_in[11];
    float* out = (float*)d_out;

    char* ws = (char*)d_ws;
    size_t off = 0;
    auto alloc = [&](size_t bytes) {
        void* p = ws + off;
        off += (bytes + 255) & ~(size_t)255;
        return p;
    };
    float* bufP = (float*)alloc((size_t)N_NODES * 128 * 4);                    // layer output fp32
    unsigned short* h_bf = (unsigned short*)alloc((size_t)N_NODES * 128 * 2);  // h bf16
    unsigned short* Wt = (unsigned short*)alloc((size_t)L_LAYERS * 128 * 128 * 2);
    unsigned short* Wa = (unsigned short*)alloc((size_t)L_LAYERS * 16 * 128 * 2);
    float* als = (float*)alloc((size_t)N_NODES * 4 * 4);
    float* ald = (float*)alloc((size_t)N_NODES * 4 * 4);
    float* pooled = (float*)alloc((size_t)G_GRAPHS * HD * 4);
    int* fill = (int*)alloc((size_t)N_NODES * 4);
    int* csr = (int*)alloc((size_t)N_NODES * MAXDEG * 4);

    hipMemsetAsync(pooled, 0, G_GRAPHS * HD * 4, stream);
    const int NPREP = L_LAYERS * 128 * 128 + L_LAYERS * 16 * 128;
    prep_kernel<<<(NPREP + 255) / 256, 256, 0, stream>>>(W, a_src, a_dst, Wt, Wa);
    scatter_kernel<<<SC_BLOCKS, 1024, 0, stream>>>(edge_index, fill, csr);

    const float* xcur = x_in;
    for (int l = 0; l < L_LAYERS; ++l) {
        gemm_mfma_kernel<<<(N_NODES + 63) / 64, 256, 0, stream>>>(
            xcur, Wt + (size_t)l * 128 * 128, Wa + (size_t)l * 16 * 128,
            h_bf, als, ald);
        agg_kernel<<<N_NODES / 4, 256, 0, stream>>>(
            h_bf, als, ald, fill, csr, conv_bias + l * 128, bufP);
        xcur = bufP;
    }

    int pool_waves = (N_NODES + POOL_CHUNK - 1) / POOL_CHUNK;
    pool_kernel<<<(pool_waves + 3) / 4, 256, 0, stream>>>(xcur, batch, pooled);
    bnfc_kernel<<<1, 256, 0, stream>>>(pooled, cond, bn_gamma, bn_beta, fc_w, fc_b, out);
}

// Round 16
// 305.849 us; speedup vs baseline: 1.5719x; 1.5719x over previous
//
#include <hip/hip_runtime.h>
#include <math.h>

#define N_NODES 50000
#define N_EDGES 800000
#define ETOT (N_EDGES + N_NODES)
#define G_GRAPHS 128
#define HD 128
#define COND_F 7
#define NFEAT 135
#define LAT 32
#define L_LAYERS 3
#define SLOPE 0.2f
#define MAXDEG 96
#define N_TEAMS 8
#define TEAM_RANGE ((N_NODES + N_TEAMS - 1) / N_TEAMS)  // 6250
#define SC_BLOCKS (N_TEAMS * 416)

typedef __attribute__((ext_vector_type(8))) short bf16x8;
typedef __attribute__((ext_vector_type(4))) float f32x4;

__device__ __forceinline__ float leaky_(float x) { return x > 0.f ? x : SLOPE * x; }

__device__ __forceinline__ unsigned short f2bf_(float f) {
    unsigned int u = __float_as_uint(f);
    u += 0x7FFF + ((u >> 16) & 1);  // round-to-nearest-even
    return (unsigned short)(u >> 16);
}
__device__ __forceinline__ float bf2f_(unsigned short b) {
    return __uint_as_float((unsigned int)b << 16);
}
__device__ __forceinline__ unsigned int pack_bf2_(float lo, float hi) {
    unsigned int ulo = __float_as_uint(lo); ulo += 0x7FFF + ((ulo >> 16) & 1);
    unsigned int uhi = __float_as_uint(hi); uhi += 0x7FFF + ((uhi >> 16) & 1);
    return (ulo >> 16) | (uhi & 0xFFFF0000u);
}

// ---------------- XCD-team CSR build ----------------
// blockIdx%8 ~ XCD (heuristic, perf-only). Team x (416 blocks, all on XCD x)
// exclusively owns dsts [x*6250, (x+1)*6250): scans the edge list cooperatively
// and writes only its own slot-major csr region + fill counters -> csr lines
// and atomics stay in ONE XCD's L2 (round-15 proved ownership kills the 47MB
// writeback; this version keeps full occupancy). Wrong mapping => merely slow.
__global__ __launch_bounds__(256) void scatter_kernel(const int* __restrict__ ei,
                                                      int* __restrict__ fill,
                                                      int* __restrict__ csr) {
    int team = blockIdx.x & (N_TEAMS - 1);
    int bt = blockIdx.x >> 3;               // block index within team
    int nbt = gridDim.x >> 3;               // blocks per team
    int tid = bt * blockDim.x + threadIdx.x;
    int stride = nbt * blockDim.x;
    int lo = team * TEAM_RANGE;
    int hi = min(lo + TEAM_RANGE, N_NODES);
    for (int i = tid; i < ETOT; i += stride) {
        int dstv = (i < N_EDGES) ? ei[N_EDGES + i] : (i - N_EDGES);
        if (dstv >= lo && dstv < hi) {
            int srcv = (i < N_EDGES) ? ei[i] : dstv;
            int slot = atomicAdd(&fill[dstv], 1);
            if (slot < MAXDEG) csr[slot * N_NODES + dstv] = srcv;
        }
    }
}

// ---------------- fused weight prep: Wt (bf16 W^T) + Wa (logit matrix) ----
__global__ void prep_kernel(const float* __restrict__ W, const float* __restrict__ a_s,
                            const float* __restrict__ a_d, unsigned short* __restrict__ Wt,
                            unsigned short* __restrict__ Wa) {
    int i = blockIdx.x * blockDim.x + threadIdx.x;
    const int NW = L_LAYERS * 128 * 128;
    if (i < NW) {
        int l = i >> 14, rem = i & 16383, k = rem >> 7, n = rem & 127;
        unsigned int u = __float_as_uint(W[i]);
        u += 0x7FFF + ((u >> 16) & 1);
        Wt[(l << 14) + n * 128 + k] = (unsigned short)(u >> 16);
        return;
    }
    int j = i - NW;
    if (j >= L_LAYERS * 16 * 128) return;
    int l = j >> 11, rem = j & 2047, c = rem >> 7, k = rem & 127;
    float v = 0.f;
    if (c < 8) {
        int h = c >> 1;
        const float* av = (c & 1) ? &a_d[l * 128 + h * 32] : &a_s[l * 128 + h * 32];
        const float* wrow = &W[(l << 14) + k * 128 + h * 32];
#pragma unroll
        for (int d = 0; d < 32; ++d) v = fmaf(wrow[d], av[d], v);
    }
    Wa[j] = f2bf_(v);
}

// ---------------- MFMA GEMM + fused attention logits ----------------
// h_bf = bf16(x @ W); al_s/al_d from an extra MFMA column-tile on wave 0.
// Measured round 11: ~13 us per dispatch (duplicate-launch differencing).
__global__ __launch_bounds__(256) void gemm_mfma_kernel(
    const float* __restrict__ x, const unsigned short* __restrict__ Wt,
    const unsigned short* __restrict__ Wa,
    unsigned short* __restrict__ h_bf, float* __restrict__ al_s,
    float* __restrict__ al_d) {
    __shared__ __align__(16) unsigned short xs[64 * 128];  // bf16, XOR-swizzled rows (256B)
    int t = threadIdx.x;
    int lane = t & 63;
    int w = t >> 6;
    int row0 = blockIdx.x * 64;

    // stage A: thread t -> row t>>2, cols (t&3)*32 .. +31 (fp32 -> bf16)
    {
        int r = t >> 2, c0 = (t & 3) * 32;
        int gr = row0 + r;
        unsigned int upk[16];
        if (gr < N_NODES) {
            const float* src = &x[(size_t)gr * 128 + c0];
#pragma unroll
            for (int i = 0; i < 8; ++i) {
                float4 v = *(const float4*)&src[i * 4];
                upk[i * 2 + 0] = pack_bf2_(v.x, v.y);
                upk[i * 2 + 1] = pack_bf2_(v.z, v.w);
            }
        } else {
#pragma unroll
            for (int i = 0; i < 16; ++i) upk[i] = 0;
        }
        char* base = (char*)xs + r * 256;
#pragma unroll
        for (int i = 0; i < 4; ++i) {
            int cb = c0 * 2 + i * 16;
            int sw = cb ^ ((r & 7) << 4);
            *(uint4*)(base + sw) = make_uint4(upk[i * 4 + 0], upk[i * 4 + 1],
                                              upk[i * 4 + 2], upk[i * 4 + 3]);
        }
    }
    int l15 = lane & 15, g16 = lane >> 4;
    int cn = w * 32;
    bf16x8 bfr[2][4];
#pragma unroll
    for (int ct = 0; ct < 2; ++ct)
#pragma unroll
        for (int ks = 0; ks < 4; ++ks)
            bfr[ct][ks] = *(const bf16x8*)&Wt[(size_t)(cn + ct * 16 + l15) * 128 + ks * 32 + g16 * 8];
    bf16x8 bfrL[4];
    if (w == 0) {
#pragma unroll
        for (int ks = 0; ks < 4; ++ks)
            bfrL[ks] = *(const bf16x8*)&Wa[l15 * 128 + ks * 32 + g16 * 8];
    }
    __syncthreads();

    f32x4 acc[4][2];
    f32x4 accL[4];
#pragma unroll
    for (int rt = 0; rt < 4; ++rt) {
#pragma unroll
        for (int ct = 0; ct < 2; ++ct) acc[rt][ct] = (f32x4){0.f, 0.f, 0.f, 0.f};
        accL[rt] = (f32x4){0.f, 0.f, 0.f, 0.f};
    }

#pragma unroll
    for (int ks = 0; ks < 4; ++ks) {
        bf16x8 af[4];
#pragma unroll
        for (int rt = 0; rt < 4; ++rt) {
            int r = rt * 16 + l15;
            int cb = ks * 64 + g16 * 16;
            af[rt] = *(const bf16x8*)((const char*)xs + r * 256 + (cb ^ ((r & 7) << 4)));
        }
#pragma unroll
        for (int rt = 0; rt < 4; ++rt)
#pragma unroll
            for (int ct = 0; ct < 2; ++ct)
                acc[rt][ct] = __builtin_amdgcn_mfma_f32_16x16x32_bf16(
                    af[rt], bfr[ct][ks], acc[rt][ct], 0, 0, 0);
        if (w == 0) {
#pragma unroll
            for (int rt = 0; rt < 4; ++rt)
                accL[rt] = __builtin_amdgcn_mfma_f32_16x16x32_bf16(
                    af[rt], bfrL[ks], accL[rt], 0, 0, 0);
        }
    }

    __syncthreads();  // all waves done reading xs; reuse it as the output tile

#pragma unroll
    for (int rt = 0; rt < 4; ++rt) {
#pragma unroll
        for (int j = 0; j < 4; ++j) {
            int r = rt * 16 + g16 * 4 + j;
            int sw = (r & 7) << 4;
            char* rowb = (char*)xs + r * 256;
            *(unsigned short*)(rowb + (((cn + l15) * 2) ^ sw)) = f2bf_(acc[rt][0][j]);
            *(unsigned short*)(rowb + (((cn + 16 + l15) * 2) ^ sw)) = f2bf_(acc[rt][1][j]);
        }
    }
    if (w == 0) {
#pragma unroll
        for (int rt = 0; rt < 4; ++rt) {
#pragma unroll
            for (int j = 0; j < 4; ++j) {
                int grow = row0 + rt * 16 + g16 * 4 + j;
                if (l15 < 8 && grow < N_NODES) {
                    float v = accL[rt][j];
                    if (l15 & 1) al_d[grow * 4 + (l15 >> 1)] = v;
                    else al_s[grow * 4 + (l15 >> 1)] = v;
                }
            }
        }
    }
    __syncthreads();
#pragma unroll
    for (int i = 0; i < 4; ++i) {
        int flat = i * 4096 + t * 16;
        int r = flat >> 8;
        int cb = flat & 255;
        uint4 v = *(const uint4*)((const char*)xs + r * 256 + (cb ^ ((r & 7) << 4)));
        int gr = row0 + r;
        if (gr < N_NODES)
            *(uint4*)((char*)&h_bf[(size_t)gr * 128] + cb) = v;
    }
}

// ---------------- per-dst softmax + aggregation (1 wave / node) ----------------
// Byte-identical to round 14 (slot-major csr reads; ~52us measured).
__global__ __launch_bounds__(256) void agg_kernel(
    const unsigned short* __restrict__ h_bf, const float* __restrict__ al_s,
    const float* __restrict__ al_d, const int* __restrict__ deg_arr,
    const int* __restrict__ csr, const float* __restrict__ bias,
    float* __restrict__ xout) {
    __shared__ float alph[4][64][4];
    __shared__ int srcs[4][64];
    __shared__ float bounce[4][160];
    int wslot = threadIdx.x >> 6;
    int wv = (blockIdx.x * blockDim.x + threadIdx.x) >> 6;
    int lane = threadIdx.x & 63;
    if (wv >= N_NODES) return;
    int node = wv;
    int deg = min(deg_arr[node], MAXDEG);
    float4 ad = *(const float4*)&al_d[node * 4];

    if (deg <= 64) {
        float e0 = -1e30f, e1 = -1e30f, e2 = -1e30f, e3 = -1e30f;
        int s_l = 0;
        if (lane < deg) {
            s_l = csr[lane * N_NODES + node];
            float4 as = *(const float4*)&al_s[s_l * 4];
            e0 = leaky_(as.x + ad.x);
            e1 = leaky_(as.y + ad.y);
            e2 = leaky_(as.z + ad.z);
            e3 = leaky_(as.w + ad.w);
        }
        float m0 = e0, m1 = e1, m2 = e2, m3 = e3;
#pragma unroll
        for (int off = 1; off < 64; off <<= 1) {
            m0 = fmaxf(m0, __shfl_xor(m0, off));
            m1 = fmaxf(m1, __shfl_xor(m1, off));
            m2 = fmaxf(m2, __shfl_xor(m2, off));
            m3 = fmaxf(m3, __shfl_xor(m3, off));
        }
        float x0 = 0.f, x1 = 0.f, x2 = 0.f, x3 = 0.f;
        if (lane < deg) {
            x0 = __expf(e0 - m0);
            x1 = __expf(e1 - m1);
            x2 = __expf(e2 - m2);
            x3 = __expf(e3 - m3);
        }
        float d0 = x0, d1 = x1, d2 = x2, d3 = x3;
#pragma unroll
        for (int off = 1; off < 64; off <<= 1) {
            d0 += __shfl_xor(d0, off);
            d1 += __shfl_xor(d1, off);
            d2 += __shfl_xor(d2, off);
            d3 += __shfl_xor(d3, off);
        }
        float i0 = 1.f / (d0 + 1e-16f), i1 = 1.f / (d1 + 1e-16f);
        float i2 = 1.f / (d2 + 1e-16f), i3 = 1.f / (d3 + 1e-16f);

        *(float4*)&alph[wslot][lane][0] =
            make_float4(x0 * i0, x1 * i1, x2 * i2, x3 * i3);
        srcs[wslot][lane] = s_l;

        int grp = lane >> 4, li = lane & 15;
        int hq = li >> 2;  // head of features 8*li .. 8*li+7
        float facc[8];
#pragma unroll
        for (int k = 0; k < 8; ++k) facc[k] = 0.f;
        int degr = (deg + 3) & ~3;  // LDS is zero-padded: branch-free chunks
        int j0 = 0;
        for (; j0 + 8 <= degr; j0 += 8) {
            int eA = j0 + grp, eB = j0 + 4 + grp;
            int sA = srcs[wslot][eA];
            int sB = srcs[wslot][eB];
            float aA = alph[wslot][eA][hq];
            float aB = alph[wslot][eB][hq];
            uint4 vA = *(const uint4*)&h_bf[(size_t)sA * 128 + li * 8];
            uint4 vB = *(const uint4*)&h_bf[(size_t)sB * 128 + li * 8];
            facc[0] = fmaf(aA, __uint_as_float(vA.x << 16), facc[0]);
            facc[1] = fmaf(aA, __uint_as_float(vA.x & 0xFFFF0000u), facc[1]);
            facc[2] = fmaf(aA, __uint_as_float(vA.y << 16), facc[2]);
            facc[3] = fmaf(aA, __uint_as_float(vA.y & 0xFFFF0000u), facc[3]);
            facc[4] = fmaf(aA, __uint_as_float(vA.z << 16), facc[4]);
            facc[5] = fmaf(aA, __uint_as_float(vA.z & 0xFFFF0000u), facc[5]);
            facc[6] = fmaf(aA, __uint_as_float(vA.w << 16), facc[6]);
            facc[7] = fmaf(aA, __uint_as_float(vA.w & 0xFFFF0000u), facc[7]);
            facc[0] = fmaf(aB, __uint_as_float(vB.x << 16), facc[0]);
            facc[1] = fmaf(aB, __uint_as_float(vB.x & 0xFFFF0000u), facc[1]);
            facc[2] = fmaf(aB, __uint_as_float(vB.y << 16), facc[2]);
            facc[3] = fmaf(aB, __uint_as_float(vB.y & 0xFFFF0000u), facc[3]);
            facc[4] = fmaf(aB, __uint_as_float(vB.z << 16), facc[4]);
            facc[5] = fmaf(aB, __uint_as_float(vB.z & 0xFFFF0000u), facc[5]);
            facc[6] = fmaf(aB, __uint_as_float(vB.w << 16), facc[6]);
            facc[7] = fmaf(aB, __uint_as_float(vB.w & 0xFFFF0000u), facc[7]);
        }
        if (j0 < degr) {
            int e = j0 + grp;
            int s = srcs[wslot][e];
            float a = alph[wslot][e][hq];
            uint4 v = *(const uint4*)&h_bf[(size_t)s * 128 + li * 8];
            facc[0] = fmaf(a, __uint_as_float(v.x << 16), facc[0]);
            facc[1] = fmaf(a, __uint_as_float(v.x & 0xFFFF0000u), facc[1]);
            facc[2] = fmaf(a, __uint_as_float(v.y << 16), facc[2]);
            facc[3] = fmaf(a, __uint_as_float(v.y & 0xFFFF0000u), facc[3]);
            facc[4] = fmaf(a, __uint_as_float(v.z << 16), facc[4]);
            facc[5] = fmaf(a, __uint_as_float(v.z & 0xFFFF0000u), facc[5]);
            facc[6] = fmaf(a, __uint_as_float(v.w << 16), facc[6]);
            facc[7] = fmaf(a, __uint_as_float(v.w & 0xFFFF0000u), facc[7]);
        }
#pragma unroll
        for (int k = 0; k < 8; ++k) {
            facc[k] += __shfl_xor(facc[k], 16);
            facc[k] += __shfl_xor(facc[k], 32);
        }
        if (grp == 0) {
            // feature li*8+k stored at [k*17+li]: 16 distinct banks per k
#pragma unroll
            for (int k = 0; k < 8; ++k) bounce[wslot][k * 17 + li] = facc[k];
        }
        // single-wave LDS write->read: ordered via lgkmcnt, no barrier needed
        int fA = lane, fB = lane + 64;
        float o0 = bounce[wslot][(fA & 7) * 17 + (fA >> 3)];
        float o1 = bounce[wslot][(fB & 7) * 17 + (fB >> 3)];
        xout[node * 128 + fA] = leaky_(o0 + bias[fA]);
        xout[node * 128 + fB] = leaky_(o1 + bias[fB]);
    } else {
        // generic fallback (64 < deg <= MAXDEG) — rare for this input
        int f0 = lane, f1 = lane + 64;
        int hA = lane >> 5;
        float acc0 = 0.f, acc1 = 0.f;
        float m0 = -1e30f, m1 = -1e30f, m2 = -1e30f, m3 = -1e30f;
        for (int e = lane; e < deg; e += 64) {
            int s = csr[e * N_NODES + node];
            float4 as = *(const float4*)&al_s[s * 4];
            m0 = fmaxf(m0, leaky_(as.x + ad.x));
            m1 = fmaxf(m1, leaky_(as.y + ad.y));
            m2 = fmaxf(m2, leaky_(as.z + ad.z));
            m3 = fmaxf(m3, leaky_(as.w + ad.w));
        }
#pragma unroll
        for (int off = 1; off < 64; off <<= 1) {
            m0 = fmaxf(m0, __shfl_xor(m0, off));
            m1 = fmaxf(m1, __shfl_xor(m1, off));
            m2 = fmaxf(m2, __shfl_xor(m2, off));
            m3 = fmaxf(m3, __shfl_xor(m3, off));
        }
        float d0 = 0.f, d1 = 0.f, d2 = 0.f, d3 = 0.f;
        for (int e = lane; e < deg; e += 64) {
            int s = csr[e * N_NODES + node];
            float4 as = *(const float4*)&al_s[s * 4];
            d0 += __expf(leaky_(as.x + ad.x) - m0);
            d1 += __expf(leaky_(as.y + ad.y) - m1);
            d2 += __expf(leaky_(as.z + ad.z) - m2);
            d3 += __expf(leaky_(as.w + ad.w) - m3);
        }
#pragma unroll
        for (int off = 1; off < 64; off <<= 1) {
            d0 += __shfl_xor(d0, off);
            d1 += __shfl_xor(d1, off);
            d2 += __shfl_xor(d2, off);
            d3 += __shfl_xor(d3, off);
        }
        float i0 = 1.f / (d0 + 1e-16f), i1 = 1.f / (d1 + 1e-16f);
        float i2 = 1.f / (d2 + 1e-16f), i3 = 1.f / (d3 + 1e-16f);
        float adA = hA ? ad.y : ad.x, adB = hA ? ad.w : ad.z;
        float mA = hA ? m1 : m0, mB = hA ? m3 : m2;
        float iA = hA ? i1 : i0, iB = hA ? i3 : i2;
        for (int e = 0; e < deg; ++e) {
            int s = csr[e * N_NODES + node];
            float asA = al_s[s * 4 + hA];
            float asB = al_s[s * 4 + 2 + hA];
            float aA = __expf(leaky_(asA + adA) - mA) * iA;
            float aB = __expf(leaky_(asB + adB) - mB) * iB;
            acc0 = fmaf(aA, bf2f_(h_bf[s * 128 + f0]), acc0);
            acc1 = fmaf(aB, bf2f_(h_bf[s * 128 + f1]), acc1);
        }
        xout[node * 128 + f0] = leaky_(acc0 + bias[f0]);
        xout[node * 128 + f1] = leaky_(acc1 + bias[f1]);
    }
}

// ---------------- pooling (batch is sorted) ----------------
#define POOL_CHUNK 128
__global__ __launch_bounds__(256) void pool_kernel(const float* __restrict__ x,
                                                   const int* __restrict__ batch,
                                                   float* __restrict__ pooled) {
    int wv = (blockIdx.x * blockDim.x + threadIdx.x) >> 6;
    int lane = threadIdx.x & 63;
    int n0 = wv * POOL_CHUNK;
    if (n0 >= N_NODES) return;
    int n1 = min(n0 + POOL_CHUNK, N_NODES);
    float a0 = 0.f, a1 = 0.f;
    int gcur = batch[n0];
    for (int n = n0; n < n1; ++n) {
        int g = batch[n];
        if (g != gcur) {
            atomicAdd(&pooled[gcur * 128 + lane], a0);
            atomicAdd(&pooled[gcur * 128 + 64 + lane], a1);
            a0 = a1 = 0.f;
            gcur = g;
        }
        a0 += x[n * 128 + lane];
        a1 += x[n * 128 + 64 + lane];
    }
    atomicAdd(&pooled[gcur * 128 + lane], a0);
    atomicAdd(&pooled[gcur * 128 + 64 + lane], a1);
}

// ---------------- BatchNorm + FC (single block; tiny) ----------------
__global__ __launch_bounds__(256) void bnfc_kernel(
    const float* __restrict__ pooled, const float* __restrict__ cond,
    const float* __restrict__ gamma, const float* __restrict__ beta,
    const float* __restrict__ fcw, const float* __restrict__ fcb,
    float* __restrict__ out) {
    __shared__ float Y[G_GRAPHS * NFEAT];
    __shared__ float scale[NFEAT], shift[NFEAT];
    int t = threadIdx.x;
    for (int idx = t; idx < G_GRAPHS * NFEAT; idx += 256) {
        int g = idx / NFEAT, f = idx % NFEAT;
        Y[idx] = (f < HD) ? pooled[g * HD + f] : cond[g * COND_F + (f - HD)];
    }
    __syncthreads();
    if (t < NFEAT) {
        float s = 0.f;
        for (int g = 0; g < G_GRAPHS; ++g) s += Y[g * NFEAT + t];
        float mean = s * (1.f / G_GRAPHS);
        float v = 0.f;
        for (int g = 0; g < G_GRAPHS; ++g) {
            float dd = Y[g * NFEAT + t] - mean;
            v += dd * dd;
        }
        v *= (1.f / G_GRAPHS);
        float inv = rsqrtf(v + 1e-5f);
        float sc = gamma[t] * inv;
        scale[t] = sc;
        shift[t] = beta[t] - mean * sc;
    }
    __syncthreads();
    for (int idx = t; idx < G_GRAPHS * NFEAT; idx += 256) {
        int f = idx % NFEAT;
        Y[idx] = Y[idx] * scale[f] + shift[f];
    }
    __syncthreads();
    for (int idx = t; idx < G_GRAPHS * LAT; idx += 256) {
        int g = idx >> 5, j = idx & 31;
        float acc = fcb[j];
        for (int f = 0; f < NFEAT; ++f) acc = fmaf(Y[g * NFEAT + f], fcw[f * LAT + j], acc);
        out[idx] = acc;
    }
}

extern "C" void kernel_launch(void* const* d_in, const int* in_sizes, int n_in,
                              void* d_out, int out_size, void* d_ws, size_t ws_size,
                              hipStream_t stream) {
    const float* x_in = (const float*)d_in[0];
    const float* cond = (const float*)d_in[1];
    const float* W = (const float*)d_in[2];
    const float* a_src = (const float*)d_in[3];
    const float* a_dst = (const float*)d_in[4];
    const float* conv_bias = (const float*)d_in[5];
    const float* bn_gamma = (const float*)d_in[6];
    const float* bn_beta = (const float*)d_in[7];
    const float* fc_w = (const float*)d_in[8];
    const float* fc_b = (const float*)d_in[9];
    const int* edge_index = (const int*)d_in[10];
    const int* batch = (const int*)d_in[11];
    float* out = (float*)d_out;

    char* ws = (char*)d_ws;
    size_t off = 0;
    auto alloc = [&](size_t bytes) {
        void* p = ws + off;
        off += (bytes + 255) & ~(size_t)255;
        return p;
    };
    float* bufP = (float*)alloc((size_t)N_NODES * 128 * 4);                    // layer output fp32
    unsigned short* h_bf = (unsigned short*)alloc((size_t)N_NODES * 128 * 2);  // h bf16
    unsigned short* Wt = (unsigned short*)alloc((size_t)L_LAYERS * 128 * 128 * 2);
    unsigned short* Wa = (unsigned short*)alloc((size_t)L_LAYERS * 16 * 128 * 2);
    float* als = (float*)alloc((size_t)N_NODES * 4 * 4);
    float* ald = (float*)alloc((size_t)N_NODES * 4 * 4);
    float* pooled = (float*)alloc((size_t)G_GRAPHS * HD * 4);
    int* fill = (int*)alloc((size_t)N_NODES * 4);
    int* csr = (int*)alloc((size_t)N_NODES * MAXDEG * 4);

    hipMemsetAsync(fill, 0, N_NODES * 4, stream);
    hipMemsetAsync(pooled, 0, G_GRAPHS * HD * 4, stream);
    const int NPREP = L_LAYERS * 128 * 128 + L_LAYERS * 16 * 128;
    prep_kernel<<<(NPREP + 255) / 256, 256, 0, stream>>>(W, a_src, a_dst, Wt, Wa);
    scatter_kernel<<<SC_BLOCKS, 256, 0, stream>>>(edge_index, fill, csr);

    const float* xcur = x_in;
    for (int l = 0; l < L_LAYERS; ++l) {
        gemm_mfma_kernel<<<(N_NODES + 63) / 64, 256, 0, stream>>>(
            xcur, Wt + (size_t)l * 128 * 128, Wa + (size_t)l * 16 * 128,
            h_bf, als, ald);
        agg_kernel<<<N_NODES / 4, 256, 0, stream>>>(
            h_bf, als, ald, fill, csr, conv_bias + l * 128, bufP);
        xcur = bufP;
    }

    int pool_waves = (N_NODES + POOL_CHUNK - 1) / POOL_CHUNK;
    pool_kernel<<<(pool_waves + 3) / 4, 256, 0, stream>>>(xcur, batch, pooled);
    bnfc_kernel<<<1, 256, 0, stream>>>(pooled, cond, bn_gamma, bn_beta, fc_w, fc_b, out);
}

// Round 17
// 305.151 us; speedup vs baseline: 1.5755x; 1.0023x over previous
//
#include <hip/hip_runtime.h>
#include <math.h>

#define N_NODES 50000
#define N_EDGES 800000
#define ETOT (N_EDGES + N_NODES)
#define G_GRAPHS 128
#define HD 128
#define COND_F 7
#define NFEAT 135
#define LAT 32
#define L_LAYERS 3
#define SLOPE 0.2f
#define MAXDEG 96
#define N_TEAMS 8
#define TEAM_RANGE ((N_NODES + N_TEAMS - 1) / N_TEAMS)  // 6250
#define SC_BLOCKS (N_TEAMS * 416)

typedef __attribute__((ext_vector_type(8))) short bf16x8;
typedef __attribute__((ext_vector_type(4))) float f32x4;

__device__ __forceinline__ float leaky_(float x) { return x > 0.f ? x : SLOPE * x; }

__device__ __forceinline__ unsigned short f2bf_(float f) {
    unsigned int u = __float_as_uint(f);
    u += 0x7FFF + ((u >> 16) & 1);  // round-to-nearest-even
    return (unsigned short)(u >> 16);
}
__device__ __forceinline__ float bf2f_(unsigned short b) {
    return __uint_as_float((unsigned int)b << 16);
}
__device__ __forceinline__ unsigned int pack_bf2_(float lo, float hi) {
    unsigned int ulo = __float_as_uint(lo); ulo += 0x7FFF + ((ulo >> 16) & 1);
    unsigned int uhi = __float_as_uint(hi); uhi += 0x7FFF + ((uhi >> 16) & 1);
    return (ulo >> 16) | (uhi & 0xFFFF0000u);
}

// ---------------- XCD-team CSR build (node-major csr) ----------------
// blockIdx%8 ~ XCD (heuristic, perf-only). Team x exclusively owns dsts
// [x*6250, ...): csr[dst*96+slot] writes land in the team's private 2.4MB
// region -> no cross-XCD line sharing (round 15/16 proved ownership is the
// writeback fix; layout is free to serve the READ side: node-major gives agg
// one 256B contiguous segment per node). Edge dsts scanned as int4; self-loops
// written directly over the owned range (no scan).
__global__ __launch_bounds__(256) void scatter_kernel(const int* __restrict__ ei,
                                                      int* __restrict__ fill,
                                                      int* __restrict__ csr) {
    int team = blockIdx.x & (N_TEAMS - 1);
    int bt = blockIdx.x >> 3;               // block index within team
    int nbt = gridDim.x >> 3;               // blocks per team
    int tid = bt * blockDim.x + threadIdx.x;
    int stride = nbt * blockDim.x;
    int lo = team * TEAM_RANGE;
    int hi = min(lo + TEAM_RANGE, N_NODES);
    const int4* d4 = (const int4*)(ei + N_EDGES);
    const int nv = N_EDGES / 4;
    for (int i = tid; i < nv; i += stride) {
        int4 d = d4[i];
        int idx = i * 4;
        if (d.x >= lo && d.x < hi) {
            int s = atomicAdd(&fill[d.x], 1);
            if (s < MAXDEG) csr[d.x * MAXDEG + s] = ei[idx + 0];
        }
        if (d.y >= lo && d.y < hi) {
            int s = atomicAdd(&fill[d.y], 1);
            if (s < MAXDEG) csr[d.y * MAXDEG + s] = ei[idx + 1];
        }
        if (d.z >= lo && d.z < hi) {
            int s = atomicAdd(&fill[d.z], 1);
            if (s < MAXDEG) csr[d.z * MAXDEG + s] = ei[idx + 2];
        }
        if (d.w >= lo && d.w < hi) {
            int s = atomicAdd(&fill[d.w], 1);
            if (s < MAXDEG) csr[d.w * MAXDEG + s] = ei[idx + 3];
        }
    }
    // self-loops: owned range only, coalesced
    for (int d = lo + tid; d < hi; d += stride) {
        int s = atomicAdd(&fill[d], 1);
        if (s < MAXDEG) csr[d * MAXDEG + s] = d;
    }
}

// ---------------- fused weight prep: Wt (bf16 W^T) + Wa (logit matrix) ----
__global__ void prep_kernel(const float* __restrict__ W, const float* __restrict__ a_s,
                            const float* __restrict__ a_d, unsigned short* __restrict__ Wt,
                            unsigned short* __restrict__ Wa) {
    int i = blockIdx.x * blockDim.x + threadIdx.x;
    const int NW = L_LAYERS * 128 * 128;
    if (i < NW) {
        int l = i >> 14, rem = i & 16383, k = rem >> 7, n = rem & 127;
        unsigned int u = __float_as_uint(W[i]);
        u += 0x7FFF + ((u >> 16) & 1);
        Wt[(l << 14) + n * 128 + k] = (unsigned short)(u >> 16);
        return;
    }
    int j = i - NW;
    if (j >= L_LAYERS * 16 * 128) return;
    int l = j >> 11, rem = j & 2047, c = rem >> 7, k = rem & 127;
    float v = 0.f;
    if (c < 8) {
        int h = c >> 1;
        const float* av = (c & 1) ? &a_d[l * 128 + h * 32] : &a_s[l * 128 + h * 32];
        const float* wrow = &W[(l << 14) + k * 128 + h * 32];
#pragma unroll
        for (int d = 0; d < 32; ++d) v = fmaf(wrow[d], av[d], v);
    }
    Wa[j] = f2bf_(v);
}

// ---------------- MFMA GEMM + fused attention logits ----------------
// h_bf = bf16(x @ W); al_s/al_d from an extra MFMA column-tile on wave 0.
// Measured round 11: ~13 us per dispatch (duplicate-launch differencing).
__global__ __launch_bounds__(256) void gemm_mfma_kernel(
    const float* __restrict__ x, const unsigned short* __restrict__ Wt,
    const unsigned short* __restrict__ Wa,
    unsigned short* __restrict__ h_bf, float* __restrict__ al_s,
    float* __restrict__ al_d) {
    __shared__ __align__(16) unsigned short xs[64 * 128];  // bf16, XOR-swizzled rows (256B)
    int t = threadIdx.x;
    int lane = t & 63;
    int w = t >> 6;
    int row0 = blockIdx.x * 64;

    // stage A: thread t -> row t>>2, cols (t&3)*32 .. +31 (fp32 -> bf16)
    {
        int r = t >> 2, c0 = (t & 3) * 32;
        int gr = row0 + r;
        unsigned int upk[16];
        if (gr < N_NODES) {
            const float* src = &x[(size_t)gr * 128 + c0];
#pragma unroll
            for (int i = 0; i < 8; ++i) {
                float4 v = *(const float4*)&src[i * 4];
                upk[i * 2 + 0] = pack_bf2_(v.x, v.y);
                upk[i * 2 + 1] = pack_bf2_(v.z, v.w);
            }
        } else {
#pragma unroll
            for (int i = 0; i < 16; ++i) upk[i] = 0;
        }
        char* base = (char*)xs + r * 256;
#pragma unroll
        for (int i = 0; i < 4; ++i) {
            int cb = c0 * 2 + i * 16;
            int sw = cb ^ ((r & 7) << 4);
            *(uint4*)(base + sw) = make_uint4(upk[i * 4 + 0], upk[i * 4 + 1],
                                              upk[i * 4 + 2], upk[i * 4 + 3]);
        }
    }
    int l15 = lane & 15, g16 = lane >> 4;
    int cn = w * 32;
    bf16x8 bfr[2][4];
#pragma unroll
    for (int ct = 0; ct < 2; ++ct)
#pragma unroll
        for (int ks = 0; ks < 4; ++ks)
            bfr[ct][ks] = *(const bf16x8*)&Wt[(size_t)(cn + ct * 16 + l15) * 128 + ks * 32 + g16 * 8];
    bf16x8 bfrL[4];
    if (w == 0) {
#pragma unroll
        for (int ks = 0; ks < 4; ++ks)
            bfrL[ks] = *(const bf16x8*)&Wa[l15 * 128 + ks * 32 + g16 * 8];
    }
    __syncthreads();

    f32x4 acc[4][2];
    f32x4 accL[4];
#pragma unroll
    for (int rt = 0; rt < 4; ++rt) {
#pragma unroll
        for (int ct = 0; ct < 2; ++ct) acc[rt][ct] = (f32x4){0.f, 0.f, 0.f, 0.f};
        accL[rt] = (f32x4){0.f, 0.f, 0.f, 0.f};
    }

#pragma unroll
    for (int ks = 0; ks < 4; ++ks) {
        bf16x8 af[4];
#pragma unroll
        for (int rt = 0; rt < 4; ++rt) {
            int r = rt * 16 + l15;
            int cb = ks * 64 + g16 * 16;
            af[rt] = *(const bf16x8*)((const char*)xs + r * 256 + (cb ^ ((r & 7) << 4)));
        }
#pragma unroll
        for (int rt = 0; rt < 4; ++rt)
#pragma unroll
            for (int ct = 0; ct < 2; ++ct)
                acc[rt][ct] = __builtin_amdgcn_mfma_f32_16x16x32_bf16(
                    af[rt], bfr[ct][ks], acc[rt][ct], 0, 0, 0);
        if (w == 0) {
#pragma unroll
            for (int rt = 0; rt < 4; ++rt)
                accL[rt] = __builtin_amdgcn_mfma_f32_16x16x32_bf16(
                    af[rt], bfrL[ks], accL[rt], 0, 0, 0);
        }
    }

    __syncthreads();  // all waves done reading xs; reuse it as the output tile

#pragma unroll
    for (int rt = 0; rt < 4; ++rt) {
#pragma unroll
        for (int j = 0; j < 4; ++j) {
            int r = rt * 16 + g16 * 4 + j;
            int sw = (r & 7) << 4;
            char* rowb = (char*)xs + r * 256;
            *(unsigned short*)(rowb + (((cn + l15) * 2) ^ sw)) = f2bf_(acc[rt][0][j]);
            *(unsigned short*)(rowb + (((cn + 16 + l15) * 2) ^ sw)) = f2bf_(acc[rt][1][j]);
        }
    }
    if (w == 0) {
#pragma unroll
        for (int rt = 0; rt < 4; ++rt) {
#pragma unroll
            for (int j = 0; j < 4; ++j) {
                int grow = row0 + rt * 16 + g16 * 4 + j;
                if (l15 < 8 && grow < N_NODES) {
                    float v = accL[rt][j];
                    if (l15 & 1) al_d[grow * 4 + (l15 >> 1)] = v;
                    else al_s[grow * 4 + (l15 >> 1)] = v;
                }
            }
        }
    }
    __syncthreads();
#pragma unroll
    for (int i = 0; i < 4; ++i) {
        int flat = i * 4096 + t * 16;
        int r = flat >> 8;
        int cb = flat & 255;
        uint4 v = *(const uint4*)((const char*)xs + r * 256 + (cb ^ ((r & 7) << 4)));
        int gr = row0 + r;
        if (gr < N_NODES)
            *(uint4*)((char*)&h_bf[(size_t)gr * 128] + cb) = v;
    }
}

// ---------------- per-dst softmax + aggregation (1 wave / node) ----------------
// Round-14 structure; csr reads node-major again (one 256B segment per node).
__global__ __launch_bounds__(256) void agg_kernel(
    const unsigned short* __restrict__ h_bf, const float* __restrict__ al_s,
    const float* __restrict__ al_d, const int* __restrict__ deg_arr,
    const int* __restrict__ csr, const float* __restrict__ bias,
    float* __restrict__ xout) {
    __shared__ float alph[4][64][4];
    __shared__ int srcs[4][64];
    __shared__ float bounce[4][160];
    int wslot = threadIdx.x >> 6;
    int wv = (blockIdx.x * blockDim.x + threadIdx.x) >> 6;
    int lane = threadIdx.x & 63;
    if (wv >= N_NODES) return;
    int node = wv;
    int deg = min(deg_arr[node], MAXDEG);
    int beg = node * MAXDEG;
    float4 ad = *(const float4*)&al_d[node * 4];

    if (deg <= 64) {
        float e0 = -1e30f, e1 = -1e30f, e2 = -1e30f, e3 = -1e30f;
        int s_l = 0;
        if (lane < deg) {
            s_l = csr[beg + lane];
            float4 as = *(const float4*)&al_s[s_l * 4];
            e0 = leaky_(as.x + ad.x);
            e1 = leaky_(as.y + ad.y);
            e2 = leaky_(as.z + ad.z);
            e3 = leaky_(as.w + ad.w);
        }
        float m0 = e0, m1 = e1, m2 = e2, m3 = e3;
#pragma unroll
        for (int off = 1; off < 64; off <<= 1) {
            m0 = fmaxf(m0, __shfl_xor(m0, off));
            m1 = fmaxf(m1, __shfl_xor(m1, off));
            m2 = fmaxf(m2, __shfl_xor(m2, off));
            m3 = fmaxf(m3, __shfl_xor(m3, off));
        }
        float x0 = 0.f, x1 = 0.f, x2 = 0.f, x3 = 0.f;
        if (lane < deg) {
            x0 = __expf(e0 - m0);
            x1 = __expf(e1 - m1);
            x2 = __expf(e2 - m2);
            x3 = __expf(e3 - m3);
        }
        float d0 = x0, d1 = x1, d2 = x2, d3 = x3;
#pragma unroll
        for (int off = 1; off < 64; off <<= 1) {
            d0 += __shfl_xor(d0, off);
            d1 += __shfl_xor(d1, off);
            d2 += __shfl_xor(d2, off);
            d3 += __shfl_xor(d3, off);
        }
        float i0 = 1.f / (d0 + 1e-16f), i1 = 1.f / (d1 + 1e-16f);
        float i2 = 1.f / (d2 + 1e-16f), i3 = 1.f / (d3 + 1e-16f);

        *(float4*)&alph[wslot][lane][0] =
            make_float4(x0 * i0, x1 * i1, x2 * i2, x3 * i3);
        srcs[wslot][lane] = s_l;

        int grp = lane >> 4, li = lane & 15;
        int hq = li >> 2;  // head of features 8*li .. 8*li+7
        float facc[8];
#pragma unroll
        for (int k = 0; k < 8; ++k) facc[k] = 0.f;
        int degr = (deg + 3) & ~3;  // LDS is zero-padded: branch-free chunks
        int j0 = 0;
        for (; j0 + 8 <= degr; j0 += 8) {
            int eA = j0 + grp, eB = j0 + 4 + grp;
            int sA = srcs[wslot][eA];
            int sB = srcs[wslot][eB];
            float aA = alph[wslot][eA][hq];
            float aB = alph[wslot][eB][hq];
            uint4 vA = *(const uint4*)&h_bf[(size_t)sA * 128 + li * 8];
            uint4 vB = *(const uint4*)&h_bf[(size_t)sB * 128 + li * 8];
            facc[0] = fmaf(aA, __uint_as_float(vA.x << 16), facc[0]);
            facc[1] = fmaf(aA, __uint_as_float(vA.x & 0xFFFF0000u), facc[1]);
            facc[2] = fmaf(aA, __uint_as_float(vA.y << 16), facc[2]);
            facc[3] = fmaf(aA, __uint_as_float(vA.y & 0xFFFF0000u), facc[3]);
            facc[4] = fmaf(aA, __uint_as_float(vA.z << 16), facc[4]);
            facc[5] = fmaf(aA, __uint_as_float(vA.z & 0xFFFF0000u), facc[5]);
            facc[6] = fmaf(aA, __uint_as_float(vA.w << 16), facc[6]);
            facc[7] = fmaf(aA, __uint_as_float(vA.w & 0xFFFF0000u), facc[7]);
            facc[0] = fmaf(aB, __uint_as_float(vB.x << 16), facc[0]);
            facc[1] = fmaf(aB, __uint_as_float(vB.x & 0xFFFF0000u), facc[1]);
            facc[2] = fmaf(aB, __uint_as_float(vB.y << 16), facc[2]);
            facc[3] = fmaf(aB, __uint_as_float(vB.y & 0xFFFF0000u), facc[3]);
            facc[4] = fmaf(aB, __uint_as_float(vB.z << 16), facc[4]);
            facc[5] = fmaf(aB, __uint_as_float(vB.z & 0xFFFF0000u), facc[5]);
            facc[6] = fmaf(aB, __uint_as_float(vB.w << 16), facc[6]);
            facc[7] = fmaf(aB, __uint_as_float(vB.w & 0xFFFF0000u), facc[7]);
        }
        if (j0 < degr) {
            int e = j0 + grp;
            int s = srcs[wslot][e];
            float a = alph[wslot][e][hq];
            uint4 v = *(const uint4*)&h_bf[(size_t)s * 128 + li * 8];
            facc[0] = fmaf(a, __uint_as_float(v.x << 16), facc[0]);
            facc[1] = fmaf(a, __uint_as_float(v.x & 0xFFFF0000u), facc[1]);
            facc[2] = fmaf(a, __uint_as_float(v.y << 16), facc[2]);
            facc[3] = fmaf(a, __uint_as_float(v.y & 0xFFFF0000u), facc[3]);
            facc[4] = fmaf(a, __uint_as_float(v.z << 16), facc[4]);
            facc[5] = fmaf(a, __uint_as_float(v.z & 0xFFFF0000u), facc[5]);
            facc[6] = fmaf(a, __uint_as_float(v.w << 16), facc[6]);
            facc[7] = fmaf(a, __uint_as_float(v.w & 0xFFFF0000u), facc[7]);
        }
#pragma unroll
        for (int k = 0; k < 8; ++k) {
            facc[k] += __shfl_xor(facc[k], 16);
            facc[k] += __shfl_xor(facc[k], 32);
        }
        if (grp == 0) {
            // feature li*8+k stored at [k*17+li]: 16 distinct banks per k
#pragma unroll
            for (int k = 0; k < 8; ++k) bounce[wslot][k * 17 + li] = facc[k];
        }
        // single-wave LDS write->read: ordered via lgkmcnt, no barrier needed
        int fA = lane, fB = lane + 64;
        float o0 = bounce[wslot][(fA & 7) * 17 + (fA >> 3)];
        float o1 = bounce[wslot][(fB & 7) * 17 + (fB >> 3)];
        xout[node * 128 + fA] = leaky_(o0 + bias[fA]);
        xout[node * 128 + fB] = leaky_(o1 + bias[fB]);
    } else {
        // generic fallback (64 < deg <= MAXDEG) — rare for this input
        int f0 = lane, f1 = lane + 64;
        int hA = lane >> 5;
        float acc0 = 0.f, acc1 = 0.f;
        int end = beg + deg;
        float m0 = -1e30f, m1 = -1e30f, m2 = -1e30f, m3 = -1e30f;
        for (int e = beg + lane; e < end; e += 64) {
            int s = csr[e];
            float4 as = *(const float4*)&al_s[s * 4];
            m0 = fmaxf(m0, leaky_(as.x + ad.x));
            m1 = fmaxf(m1, leaky_(as.y + ad.y));
            m2 = fmaxf(m2, leaky_(as.z + ad.z));
            m3 = fmaxf(m3, leaky_(as.w + ad.w));
        }
#pragma unroll
        for (int off = 1; off < 64; off <<= 1) {
            m0 = fmaxf(m0, __shfl_xor(m0, off));
            m1 = fmaxf(m1, __shfl_xor(m1, off));
            m2 = fmaxf(m2, __shfl_xor(m2, off));
            m3 = fmaxf(m3, __shfl_xor(m3, off));
        }
        float d0 = 0.f, d1 = 0.f, d2 = 0.f, d3 = 0.f;
        for (int e = beg + lane; e < end; e += 64) {
            int s = csr[e];
            float4 as = *(const float4*)&al_s[s * 4];
            d0 += __expf(leaky_(as.x + ad.x) - m0);
            d1 += __expf(leaky_(as.y + ad.y) - m1);
            d2 += __expf(leaky_(as.z + ad.z) - m2);
            d3 += __expf(leaky_(as.w + ad.w) - m3);
        }
#pragma unroll
        for (int off = 1; off < 64; off <<= 1) {
            d0 += __shfl_xor(d0, off);
            d1 += __shfl_xor(d1, off);
            d2 += __shfl_xor(d2, off);
            d3 += __shfl_xor(d3, off);
        }
        float i0 = 1.f / (d0 + 1e-16f), i1 = 1.f / (d1 + 1e-16f);
        float i2 = 1.f / (d2 + 1e-16f), i3 = 1.f / (d3 + 1e-16f);
        float adA = hA ? ad.y : ad.x, adB = hA ? ad.w : ad.z;
        float mA = hA ? m1 : m0, mB = hA ? m3 : m2;
        float iA = hA ? i1 : i0, iB = hA ? i3 : i2;
        for (int e = beg; e < end; ++e) {
            int s = csr[e];
            float asA = al_s[s * 4 + hA];
            float asB = al_s[s * 4 + 2 + hA];
            float aA = __expf(leaky_(asA + adA) - mA) * iA;
            float aB = __expf(leaky_(asB + adB) - mB) * iB;
            acc0 = fmaf(aA, bf2f_(h_bf[s * 128 + f0]), acc0);
            acc1 = fmaf(aB, bf2f_(h_bf[s * 128 + f1]), acc1);
        }
        xout[node * 128 + f0] = leaky_(acc0 + bias[f0]);
        xout[node * 128 + f1] = leaky_(acc1 + bias[f1]);
    }
}

// ---------------- pooling (batch is sorted) ----------------
#define POOL_CHUNK 128
__global__ __launch_bounds__(256) void pool_kernel(const float* __restrict__ x,
                                                   const int* __restrict__ batch,
                                                   float* __restrict__ pooled) {
    int wv = (blockIdx.x * blockDim.x + threadIdx.x) >> 6;
    int lane = threadIdx.x & 63;
    int n0 = wv * POOL_CHUNK;
    if (n0 >= N_NODES) return;
    int n1 = min(n0 + POOL_CHUNK, N_NODES);
    float a0 = 0.f, a1 = 0.f;
    int gcur = batch[n0];
    for (int n = n0; n < n1; ++n) {
        int g = batch[n];
        if (g != gcur) {
            atomicAdd(&pooled[gcur * 128 + lane], a0);
            atomicAdd(&pooled[gcur * 128 + 64 + lane], a1);
            a0 = a1 = 0.f;
            gcur = g;
        }
        a0 += x[n * 128 + lane];
        a1 += x[n * 128 + 64 + lane];
    }
    atomicAdd(&pooled[gcur * 128 + lane], a0);
    atomicAdd(&pooled[gcur * 128 + 64 + lane], a1);
}

// ---------------- BatchNorm + FC (single block; tiny) ----------------
__global__ __launch_bounds__(256) void bnfc_kernel(
    const float* __restrict__ pooled, const float* __restrict__ cond,
    const float* __restrict__ gamma, const float* __restrict__ beta,
    const float* __restrict__ fcw, const float* __restrict__ fcb,
    float* __restrict__ out) {
    __shared__ float Y[G_GRAPHS * NFEAT];
    __shared__ float scale[NFEAT], shift[NFEAT];
    int t = threadIdx.x;
    for (int idx = t; idx < G_GRAPHS * NFEAT; idx += 256) {
        int g = idx / NFEAT, f = idx % NFEAT;
        Y[idx] = (f < HD) ? pooled[g * HD + f] : cond[g * COND_F + (f - HD)];
    }
    __syncthreads();
    if (t < NFEAT) {
        float s = 0.f;
        for (int g = 0; g < G_GRAPHS; ++g) s += Y[g * NFEAT + t];
        float mean = s * (1.f / G_GRAPHS);
        float v = 0.f;
        for (int g = 0; g < G_GRAPHS; ++g) {
            float dd = Y[g * NFEAT + t] - mean;
            v += dd * dd;
        }
        v *= (1.f / G_GRAPHS);
        float inv = rsqrtf(v + 1e-5f);
        float sc = gamma[t] * inv;
        scale[t] = sc;
        shift[t] = beta[t] - mean * sc;
    }
    __syncthreads();
    for (int idx = t; idx < G_GRAPHS * NFEAT; idx += 256) {
        int f = idx % NFEAT;
        Y[idx] = Y[idx] * scale[f] + shift[f];
    }
    __syncthreads();
    for (int idx = t; idx < G_GRAPHS * LAT; idx += 256) {
        int g = idx >> 5, j = idx & 31;
        float acc = fcb[j];
        for (int f = 0; f < NFEAT; ++f) acc = fmaf(Y[g * NFEAT + f], fcw[f * LAT + j], acc);
        out[idx] = acc;
    }
}

extern "C" void kernel_launch(void* const* d_in, const int* in_sizes, int n_in,
                              void* d_out, int out_size, void* d_ws, size_t ws_size,
                              hipStream_t stream) {
    const float* x_in = (const float*)d_in[0];
    const float* cond = (const float*)d_in[1];
    const float* W = (const float*)d_in[2];
    const float* a_src = (const float*)d_in[3];
    const float* a_dst = (const float*)d_in[4];
    const float* conv_bias = (const float*)d_in[5];
    const float* bn_gamma = (const float*)d_in[6];
    const float* bn_beta = (const float*)d_in[7];
    const float* fc_w = (const float*)d_in[8];
    const float* fc_b = (const float*)d_in[9];
    const int* edge_index = (const int*)d_in[10];
    const int* batch = (const int*)d_in[11];
    float* out = (float*)d_out;

    char* ws = (char*)d_ws;
    size_t off = 0;
    auto alloc = [&](size_t bytes) {
        void* p = ws + off;
        off += (bytes + 255) & ~(size_t)255;
        return p;
    };
    float* bufP = (float*)alloc((size_t)N_NODES * 128 * 4);                    // layer output fp32
    unsigned short* h_bf = (unsigned short*)alloc((size_t)N_NODES * 128 * 2);  // h bf16
    unsigned short* Wt = (unsigned short*)alloc((size_t)L_LAYERS * 128 * 128 * 2);
    unsigned short* Wa = (unsigned short*)alloc((size_t)L_LAYERS * 16 * 128 * 2);
    float* als = (float*)alloc((size_t)N_NODES * 4 * 4);
    float* ald = (float*)alloc((size_t)N_NODES * 4 * 4);
    float* pooled = (float*)alloc((size_t)G_GRAPHS * HD * 4);
    int* fill = (int*)alloc((size_t)N_NODES * 4);
    int* csr = (int*)alloc((size_t)N_NODES * MAXDEG * 4);

    hipMemsetAsync(fill, 0, N_NODES * 4, stream);
    hipMemsetAsync(pooled, 0, G_GRAPHS * HD * 4, stream);
    const int NPREP = L_LAYERS * 128 * 128 + L_LAYERS * 16 * 128;
    prep_kernel<<<(NPREP + 255) / 256, 256, 0, stream>>>(W, a_src, a_dst, Wt, Wa);
    scatter_kernel<<<SC_BLOCKS, 256, 0, stream>>>(edge_index, fill, csr);

    const float* xcur = x_in;
    for (int l = 0; l < L_LAYERS; ++l) {
        gemm_mfma_kernel<<<(N_NODES + 63) / 64, 256, 0, stream>>>(
            xcur, Wt + (size_t)l * 128 * 128, Wa + (size_t)l * 16 * 128,
            h_bf, als, ald);
        agg_kernel<<<N_NODES / 4, 256, 0, stream>>>(
            h_bf, als, ald, fill, csr, conv_bias + l * 128, bufP);
        xcur = bufP;
    }

    int pool_waves = (N_NODES + POOL_CHUNK - 1) / POOL_CHUNK;
    pool_kernel<<<(pool_waves + 3) / 4, 256, 0, stream>>>(xcur, batch, pooled);
    bnfc_kernel<<<1, 256, 0, stream>>>(pooled, cond, bn_gamma, bn_beta, fc_w, fc_b, out);
}

// Round 18
// 272.780 us; speedup vs baseline: 1.7624x; 1.1187x over previous
//
#include <hip/hip_runtime.h>
#include <math.h>

#define N_NODES 50000
#define N_EDGES 800000
#define ETOT (N_EDGES + N_NODES)
#define G_GRAPHS 128
#define HD 128
#define COND_F 7
#define NFEAT 135
#define LAT 32
#define L_LAYERS 3
#define SLOPE 0.2f
#define MAXDEG 96
#define N_TEAMS 8
#define TEAM_RANGE ((N_NODES + N_TEAMS - 1) / N_TEAMS)  // 6250
#define SC_BLOCKS (N_TEAMS * 416)

typedef __attribute__((ext_vector_type(8))) short bf16x8;
typedef __attribute__((ext_vector_type(4))) float f32x4;

__device__ __forceinline__ float leaky_(float x) { return x > 0.f ? x : SLOPE * x; }

__device__ __forceinline__ unsigned short f2bf_(float f) {
    unsigned int u = __float_as_uint(f);
    u += 0x7FFF + ((u >> 16) & 1);  // round-to-nearest-even
    return (unsigned short)(u >> 16);
}
__device__ __forceinline__ float bf2f_(unsigned short b) {
    return __uint_as_float((unsigned int)b << 16);
}
__device__ __forceinline__ unsigned int pack_bf2_(float lo, float hi) {
    unsigned int ulo = __float_as_uint(lo); ulo += 0x7FFF + ((ulo >> 16) & 1);
    unsigned int uhi = __float_as_uint(hi); uhi += 0x7FFF + ((uhi >> 16) & 1);
    return (ulo >> 16) | (uhi & 0xFFFF0000u);
}

// ---------------- XCD-team CSR build (node-major csr) ----------------
// blockIdx%8 ~ XCD (heuristic, perf-only). Team x exclusively owns dsts
// [x*6250, ...): csr[dst*96+slot] writes land in the team's private 2.4MB
// region -> no cross-XCD line sharing. Node-major serves agg's read side
// (one 256B contiguous segment per node).
__global__ __launch_bounds__(256) void scatter_kernel(const int* __restrict__ ei,
                                                      int* __restrict__ fill,
                                                      int* __restrict__ csr) {
    int team = blockIdx.x & (N_TEAMS - 1);
    int bt = blockIdx.x >> 3;               // block index within team
    int nbt = gridDim.x >> 3;               // blocks per team
    int tid = bt * blockDim.x + threadIdx.x;
    int stride = nbt * blockDim.x;
    int lo = team * TEAM_RANGE;
    int hi = min(lo + TEAM_RANGE, N_NODES);
    const int4* d4 = (const int4*)(ei + N_EDGES);
    const int nv = N_EDGES / 4;
    for (int i = tid; i < nv; i += stride) {
        int4 d = d4[i];
        int idx = i * 4;
        if (d.x >= lo && d.x < hi) {
            int s = atomicAdd(&fill[d.x], 1);
            if (s < MAXDEG) csr[d.x * MAXDEG + s] = ei[idx + 0];
        }
        if (d.y >= lo && d.y < hi) {
            int s = atomicAdd(&fill[d.y], 1);
            if (s < MAXDEG) csr[d.y * MAXDEG + s] = ei[idx + 1];
        }
        if (d.z >= lo && d.z < hi) {
            int s = atomicAdd(&fill[d.z], 1);
            if (s < MAXDEG) csr[d.z * MAXDEG + s] = ei[idx + 2];
        }
        if (d.w >= lo && d.w < hi) {
            int s = atomicAdd(&fill[d.w], 1);
            if (s < MAXDEG) csr[d.w * MAXDEG + s] = ei[idx + 3];
        }
    }
    // self-loops: owned range only, coalesced
    for (int d = lo + tid; d < hi; d += stride) {
        int s = atomicAdd(&fill[d], 1);
        if (s < MAXDEG) csr[d * MAXDEG + s] = d;
    }
}

// ---------------- fused weight prep: Wt (bf16 W^T) + Wa (logit matrix) ----
__global__ void prep_kernel(const float* __restrict__ W, const float* __restrict__ a_s,
                            const float* __restrict__ a_d, unsigned short* __restrict__ Wt,
                            unsigned short* __restrict__ Wa) {
    int i = blockIdx.x * blockDim.x + threadIdx.x;
    const int NW = L_LAYERS * 128 * 128;
    if (i < NW) {
        int l = i >> 14, rem = i & 16383, k = rem >> 7, n = rem & 127;
        unsigned int u = __float_as_uint(W[i]);
        u += 0x7FFF + ((u >> 16) & 1);
        Wt[(l << 14) + n * 128 + k] = (unsigned short)(u >> 16);
        return;
    }
    int j = i - NW;
    if (j >= L_LAYERS * 16 * 128) return;
    int l = j >> 11, rem = j & 2047, c = rem >> 7, k = rem & 127;
    float v = 0.f;
    if (c < 8) {
        int h = c >> 1;
        const float* av = (c & 1) ? &a_d[l * 128 + h * 32] : &a_s[l * 128 + h * 32];
        const float* wrow = &W[(l << 14) + k * 128 + h * 32];
#pragma unroll
        for (int d = 0; d < 32; ++d) v = fmaf(wrow[d], av[d], v);
    }
    Wa[j] = f2bf_(v);
}

// ---------------- MFMA GEMM + fused attention logits ----------------
// h_bf = bf16(x @ W); al_s/al_d from an extra MFMA column-tile on wave 0.
// Measured round 11: ~13 us per dispatch (duplicate-launch differencing).
__global__ __launch_bounds__(256) void gemm_mfma_kernel(
    const float* __restrict__ x, const unsigned short* __restrict__ Wt,
    const unsigned short* __restrict__ Wa,
    unsigned short* __restrict__ h_bf, float* __restrict__ al_s,
    float* __restrict__ al_d) {
    __shared__ __align__(16) unsigned short xs[64 * 128];  // bf16, XOR-swizzled rows (256B)
    int t = threadIdx.x;
    int lane = t & 63;
    int w = t >> 6;
    int row0 = blockIdx.x * 64;

    // stage A: thread t -> row t>>2, cols (t&3)*32 .. +31 (fp32 -> bf16)
    {
        int r = t >> 2, c0 = (t & 3) * 32;
        int gr = row0 + r;
        unsigned int upk[16];
        if (gr < N_NODES) {
            const float* src = &x[(size_t)gr * 128 + c0];
#pragma unroll
            for (int i = 0; i < 8; ++i) {
                float4 v = *(const float4*)&src[i * 4];
                upk[i * 2 + 0] = pack_bf2_(v.x, v.y);
                upk[i * 2 + 1] = pack_bf2_(v.z, v.w);
            }
        } else {
#pragma unroll
            for (int i = 0; i < 16; ++i) upk[i] = 0;
        }
        char* base = (char*)xs + r * 256;
#pragma unroll
        for (int i = 0; i < 4; ++i) {
            int cb = c0 * 2 + i * 16;
            int sw = cb ^ ((r & 7) << 4);
            *(uint4*)(base + sw) = make_uint4(upk[i * 4 + 0], upk[i * 4 + 1],
                                              upk[i * 4 + 2], upk[i * 4 + 3]);
        }
    }
    int l15 = lane & 15, g16 = lane >> 4;
    int cn = w * 32;
    bf16x8 bfr[2][4];
#pragma unroll
    for (int ct = 0; ct < 2; ++ct)
#pragma unroll
        for (int ks = 0; ks < 4; ++ks)
            bfr[ct][ks] = *(const bf16x8*)&Wt[(size_t)(cn + ct * 16 + l15) * 128 + ks * 32 + g16 * 8];
    bf16x8 bfrL[4];
    if (w == 0) {
#pragma unroll
        for (int ks = 0; ks < 4; ++ks)
            bfrL[ks] = *(const bf16x8*)&Wa[l15 * 128 + ks * 32 + g16 * 8];
    }
    __syncthreads();

    f32x4 acc[4][2];
    f32x4 accL[4];
#pragma unroll
    for (int rt = 0; rt < 4; ++rt) {
#pragma unroll
        for (int ct = 0; ct < 2; ++ct) acc[rt][ct] = (f32x4){0.f, 0.f, 0.f, 0.f};
        accL[rt] = (f32x4){0.f, 0.f, 0.f, 0.f};
    }

#pragma unroll
    for (int ks = 0; ks < 4; ++ks) {
        bf16x8 af[4];
#pragma unroll
        for (int rt = 0; rt < 4; ++rt) {
            int r = rt * 16 + l15;
            int cb = ks * 64 + g16 * 16;
            af[rt] = *(const bf16x8*)((const char*)xs + r * 256 + (cb ^ ((r & 7) << 4)));
        }
#pragma unroll
        for (int rt = 0; rt < 4; ++rt)
#pragma unroll
            for (int ct = 0; ct < 2; ++ct)
                acc[rt][ct] = __builtin_amdgcn_mfma_f32_16x16x32_bf16(
                    af[rt], bfr[ct][ks], acc[rt][ct], 0, 0, 0);
        if (w == 0) {
#pragma unroll
            for (int rt = 0; rt < 4; ++rt)
                accL[rt] = __builtin_amdgcn_mfma_f32_16x16x32_bf16(
                    af[rt], bfrL[ks], accL[rt], 0, 0, 0);
        }
    }

    __syncthreads();  // all waves done reading xs; reuse it as the output tile

#pragma unroll
    for (int rt = 0; rt < 4; ++rt) {
#pragma unroll
        for (int j = 0; j < 4; ++j) {
            int r = rt * 16 + g16 * 4 + j;
            int sw = (r & 7) << 4;
            char* rowb = (char*)xs + r * 256;
            *(unsigned short*)(rowb + (((cn + l15) * 2) ^ sw)) = f2bf_(acc[rt][0][j]);
            *(unsigned short*)(rowb + (((cn + 16 + l15) * 2) ^ sw)) = f2bf_(acc[rt][1][j]);
        }
    }
    if (w == 0) {
#pragma unroll
        for (int rt = 0; rt < 4; ++rt) {
#pragma unroll
            for (int j = 0; j < 4; ++j) {
                int grow = row0 + rt * 16 + g16 * 4 + j;
                if (l15 < 8 && grow < N_NODES) {
                    float v = accL[rt][j];
                    if (l15 & 1) al_d[grow * 4 + (l15 >> 1)] = v;
                    else al_s[grow * 4 + (l15 >> 1)] = v;
                }
            }
        }
    }
    __syncthreads();
#pragma unroll
    for (int i = 0; i < 4; ++i) {
        int flat = i * 4096 + t * 16;
        int r = flat >> 8;
        int cb = flat & 255;
        uint4 v = *(const uint4*)((const char*)xs + r * 256 + (cb ^ ((r & 7) << 4)));
        int gr = row0 + r;
        if (gr < N_NODES)
            *(uint4*)((char*)&h_bf[(size_t)gr * 128] + cb) = v;
    }
}

// ---------------- per-dst softmax + aggregation (1 wave / node) ----------------
// Byte-identical to round 17 (node-major csr; ~50.7us measured, near its
// compulsory-traffic floor: FETCH ~97MB = 8 XCDs x 12.8MB of h).
__global__ __launch_bounds__(256) void agg_kernel(
    const unsigned short* __restrict__ h_bf, const float* __restrict__ al_s,
    const float* __restrict__ al_d, const int* __restrict__ deg_arr,
    const int* __restrict__ csr, const float* __restrict__ bias,
    float* __restrict__ xout) {
    __shared__ float alph[4][64][4];
    __shared__ int srcs[4][64];
    __shared__ float bounce[4][160];
    int wslot = threadIdx.x >> 6;
    int wv = (blockIdx.x * blockDim.x + threadIdx.x) >> 6;
    int lane = threadIdx.x & 63;
    if (wv >= N_NODES) return;
    int node = wv;
    int deg = min(deg_arr[node], MAXDEG);
    int beg = node * MAXDEG;
    float4 ad = *(const float4*)&al_d[node * 4];

    if (deg <= 64) {
        float e0 = -1e30f, e1 = -1e30f, e2 = -1e30f, e3 = -1e30f;
        int s_l = 0;
        if (lane < deg) {
            s_l = csr[beg + lane];
            float4 as = *(const float4*)&al_s[s_l * 4];
            e0 = leaky_(as.x + ad.x);
            e1 = leaky_(as.y + ad.y);
            e2 = leaky_(as.z + ad.z);
            e3 = leaky_(as.w + ad.w);
        }
        float m0 = e0, m1 = e1, m2 = e2, m3 = e3;
#pragma unroll
        for (int off = 1; off < 64; off <<= 1) {
            m0 = fmaxf(m0, __shfl_xor(m0, off));
            m1 = fmaxf(m1, __shfl_xor(m1, off));
            m2 = fmaxf(m2, __shfl_xor(m2, off));
            m3 = fmaxf(m3, __shfl_xor(m3, off));
        }
        float x0 = 0.f, x1 = 0.f, x2 = 0.f, x3 = 0.f;
        if (lane < deg) {
            x0 = __expf(e0 - m0);
            x1 = __expf(e1 - m1);
            x2 = __expf(e2 - m2);
            x3 = __expf(e3 - m3);
        }
        float d0 = x0, d1 = x1, d2 = x2, d3 = x3;
#pragma unroll
        for (int off = 1; off < 64; off <<= 1) {
            d0 += __shfl_xor(d0, off);
            d1 += __shfl_xor(d1, off);
            d2 += __shfl_xor(d2, off);
            d3 += __shfl_xor(d3, off);
        }
        float i0 = 1.f / (d0 + 1e-16f), i1 = 1.f / (d1 + 1e-16f);
        float i2 = 1.f / (d2 + 1e-16f), i3 = 1.f / (d3 + 1e-16f);

        *(float4*)&alph[wslot][lane][0] =
            make_float4(x0 * i0, x1 * i1, x2 * i2, x3 * i3);
        srcs[wslot][lane] = s_l;

        int grp = lane >> 4, li = lane & 15;
        int hq = li >> 2;  // head of features 8*li .. 8*li+7
        float facc[8];
#pragma unroll
        for (int k = 0; k < 8; ++k) facc[k] = 0.f;
        int degr = (deg + 3) & ~3;  // LDS is zero-padded: branch-free chunks
        int j0 = 0;
        for (; j0 + 8 <= degr; j0 += 8) {
            int eA = j0 + grp, eB = j0 + 4 + grp;
            int sA = srcs[wslot][eA];
            int sB = srcs[wslot][eB];
            float aA = alph[wslot][eA][hq];
            float aB = alph[wslot][eB][hq];
            uint4 vA = *(const uint4*)&h_bf[(size_t)sA * 128 + li * 8];
            uint4 vB = *(const uint4*)&h_bf[(size_t)sB * 128 + li * 8];
            facc[0] = fmaf(aA, __uint_as_float(vA.x << 16), facc[0]);
            facc[1] = fmaf(aA, __uint_as_float(vA.x & 0xFFFF0000u), facc[1]);
            facc[2] = fmaf(aA, __uint_as_float(vA.y << 16), facc[2]);
            facc[3] = fmaf(aA, __uint_as_float(vA.y & 0xFFFF0000u), facc[3]);
            facc[4] = fmaf(aA, __uint_as_float(vA.z << 16), facc[4]);
            facc[5] = fmaf(aA, __uint_as_float(vA.z & 0xFFFF0000u), facc[5]);
            facc[6] = fmaf(aA, __uint_as_float(vA.w << 16), facc[6]);
            facc[7] = fmaf(aA, __uint_as_float(vA.w & 0xFFFF0000u), facc[7]);
            facc[0] = fmaf(aB, __uint_as_float(vB.x << 16), facc[0]);
            facc[1] = fmaf(aB, __uint_as_float(vB.x & 0xFFFF0000u), facc[1]);
            facc[2] = fmaf(aB, __uint_as_float(vB.y << 16), facc[2]);
            facc[3] = fmaf(aB, __uint_as_float(vB.y & 0xFFFF0000u), facc[3]);
            facc[4] = fmaf(aB, __uint_as_float(vB.z << 16), facc[4]);
            facc[5] = fmaf(aB, __uint_as_float(vB.z & 0xFFFF0000u), facc[5]);
            facc[6] = fmaf(aB, __uint_as_float(vB.w << 16), facc[6]);
            facc[7] = fmaf(aB, __uint_as_float(vB.w & 0xFFFF0000u), facc[7]);
        }
        if (j0 < degr) {
            int e = j0 + grp;
            int s = srcs[wslot][e];
            float a = alph[wslot][e][hq];
            uint4 v = *(const uint4*)&h_bf[(size_t)s * 128 + li * 8];
            facc[0] = fmaf(a, __uint_as_float(v.x << 16), facc[0]);
            facc[1] = fmaf(a, __uint_as_float(v.x & 0xFFFF0000u), facc[1]);
            facc[2] = fmaf(a, __uint_as_float(v.y << 16), facc[2]);
            facc[3] = fmaf(a, __uint_as_float(v.y & 0xFFFF0000u), facc[3]);
            facc[4] = fmaf(a, __uint_as_float(v.z << 16), facc[4]);
            facc[5] = fmaf(a, __uint_as_float(v.z & 0xFFFF0000u), facc[5]);
            facc[6] = fmaf(a, __uint_as_float(v.w << 16), facc[6]);
            facc[7] = fmaf(a, __uint_as_float(v.w & 0xFFFF0000u), facc[7]);
        }
#pragma unroll
        for (int k = 0; k < 8; ++k) {
            facc[k] += __shfl_xor(facc[k], 16);
            facc[k] += __shfl_xor(facc[k], 32);
        }
        if (grp == 0) {
            // feature li*8+k stored at [k*17+li]: 16 distinct banks per k
#pragma unroll
            for (int k = 0; k < 8; ++k) bounce[wslot][k * 17 + li] = facc[k];
        }
        // single-wave LDS write->read: ordered via lgkmcnt, no barrier needed
        int fA = lane, fB = lane + 64;
        float o0 = bounce[wslot][(fA & 7) * 17 + (fA >> 3)];
        float o1 = bounce[wslot][(fB & 7) * 17 + (fB >> 3)];
        xout[node * 128 + fA] = leaky_(o0 + bias[fA]);
        xout[node * 128 + fB] = leaky_(o1 + bias[fB]);
    } else {
        // generic fallback (64 < deg <= MAXDEG) — rare for this input
        int f0 = lane, f1 = lane + 64;
        int hA = lane >> 5;
        float acc0 = 0.f, acc1 = 0.f;
        int end = beg + deg;
        float m0 = -1e30f, m1 = -1e30f, m2 = -1e30f, m3 = -1e30f;
        for (int e = beg + lane; e < end; e += 64) {
            int s = csr[e];
            float4 as = *(const float4*)&al_s[s * 4];
            m0 = fmaxf(m0, leaky_(as.x + ad.x));
            m1 = fmaxf(m1, leaky_(as.y + ad.y));
            m2 = fmaxf(m2, leaky_(as.z + ad.z));
            m3 = fmaxf(m3, leaky_(as.w + ad.w));
        }
#pragma unroll
        for (int off = 1; off < 64; off <<= 1) {
            m0 = fmaxf(m0, __shfl_xor(m0, off));
            m1 = fmaxf(m1, __shfl_xor(m1, off));
            m2 = fmaxf(m2, __shfl_xor(m2, off));
            m3 = fmaxf(m3, __shfl_xor(m3, off));
        }
        float d0 = 0.f, d1 = 0.f, d2 = 0.f, d3 = 0.f;
        for (int e = beg + lane; e < end; e += 64) {
            int s = csr[e];
            float4 as = *(const float4*)&al_s[s * 4];
            d0 += __expf(leaky_(as.x + ad.x) - m0);
            d1 += __expf(leaky_(as.y + ad.y) - m1);
            d2 += __expf(leaky_(as.z + ad.z) - m2);
            d3 += __expf(leaky_(as.w + ad.w) - m3);
        }
#pragma unroll
        for (int off = 1; off < 64; off <<= 1) {
            d0 += __shfl_xor(d0, off);
            d1 += __shfl_xor(d1, off);
            d2 += __shfl_xor(d2, off);
            d3 += __shfl_xor(d3, off);
        }
        float i0 = 1.f / (d0 + 1e-16f), i1 = 1.f / (d1 + 1e-16f);
        float i2 = 1.f / (d2 + 1e-16f), i3 = 1.f / (d3 + 1e-16f);
        float adA = hA ? ad.y : ad.x, adB = hA ? ad.w : ad.z;
        float mA = hA ? m1 : m0, mB = hA ? m3 : m2;
        float iA = hA ? i1 : i0, iB = hA ? i3 : i2;
        for (int e = beg; e < end; ++e) {
            int s = csr[e];
            float asA = al_s[s * 4 + hA];
            float asB = al_s[s * 4 + 2 + hA];
            float aA = __expf(leaky_(asA + adA) - mA) * iA;
            float aB = __expf(leaky_(asB + adB) - mB) * iB;
            acc0 = fmaf(aA, bf2f_(h_bf[s * 128 + f0]), acc0);
            acc1 = fmaf(aB, bf2f_(h_bf[s * 128 + f1]), acc1);
        }
        xout[node * 128 + f0] = leaky_(acc0 + bias[f0]);
        xout[node * 128 + f1] = leaky_(acc1 + bias[f1]);
    }
}

// ---------------- pooling (batch is sorted) ----------------
// POOL_CHUNK 128->16: 3125 waves (was 391) -> latency-parallel, HBM-bound.
// Boundary flushes via atomicAdd (128 boundaries total; pooled is L2-resident).
#define POOL_CHUNK 16
__global__ __launch_bounds__(256) void pool_kernel(const float* __restrict__ x,
                                                   const int* __restrict__ batch,
                                                   float* __restrict__ pooled) {
    int wv = (blockIdx.x * blockDim.x + threadIdx.x) >> 6;
    int lane = threadIdx.x & 63;
    int n0 = wv * POOL_CHUNK;
    if (n0 >= N_NODES) return;
    int n1 = min(n0 + POOL_CHUNK, N_NODES);
    float a0 = 0.f, a1 = 0.f;
    int gcur = batch[n0];
    for (int n = n0; n < n1; ++n) {
        int g = batch[n];
        if (g != gcur) {
            atomicAdd(&pooled[gcur * 128 + lane], a0);
            atomicAdd(&pooled[gcur * 128 + 64 + lane], a1);
            a0 = a1 = 0.f;
            gcur = g;
        }
        a0 += x[n * 128 + lane];
        a1 += x[n * 128 + 64 + lane];
    }
    atomicAdd(&pooled[gcur * 128 + lane], a0);
    atomicAdd(&pooled[gcur * 128 + 64 + lane], a1);
}

// ---------------- BatchNorm + FC (single block; tiny) ----------------
__global__ __launch_bounds__(256) void bnfc_kernel(
    const float* __restrict__ pooled, const float* __restrict__ cond,
    const float* __restrict__ gamma, const float* __restrict__ beta,
    const float* __restrict__ fcw, const float* __restrict__ fcb,
    float* __restrict__ out) {
    __shared__ float Y[G_GRAPHS * NFEAT];
    __shared__ float scale[NFEAT], shift[NFEAT];
    int t = threadIdx.x;
    for (int idx = t; idx < G_GRAPHS * NFEAT; idx += 256) {
        int g = idx / NFEAT, f = idx % NFEAT;
        Y[idx] = (f < HD) ? pooled[g * HD + f] : cond[g * COND_F + (f - HD)];
    }
    __syncthreads();
    if (t < NFEAT) {
        float s = 0.f;
        for (int g = 0; g < G_GRAPHS; ++g) s += Y[g * NFEAT + t];
        float mean = s * (1.f / G_GRAPHS);
        float v = 0.f;
        for (int g = 0; g < G_GRAPHS; ++g) {
            float dd = Y[g * NFEAT + t] - mean;
            v += dd * dd;
        }
        v *= (1.f / G_GRAPHS);
        float inv = rsqrtf(v + 1e-5f);
        float sc = gamma[t] * inv;
        scale[t] = sc;
        shift[t] = beta[t] - mean * sc;
    }
    __syncthreads();
    for (int idx = t; idx < G_GRAPHS * NFEAT; idx += 256) {
        int f = idx % NFEAT;
        Y[idx] = Y[idx] * scale[f] + shift[f];
    }
    __syncthreads();
    for (int idx = t; idx < G_GRAPHS * LAT; idx += 256) {
        int g = idx >> 5, j = idx & 31;
        float acc = fcb[j];
        for (int f = 0; f < NFEAT; ++f) acc = fmaf(Y[g * NFEAT + f], fcw[f * LAT + j], acc);
        out[idx] = acc;
    }
}

extern "C" void kernel_launch(void* const* d_in, const int* in_sizes, int n_in,
                              void* d_out, int out_size, void* d_ws, size_t ws_size,
                              hipStream_t stream) {
    const float* x_in = (const float*)d_in[0];
    const float* cond = (const float*)d_in[1];
    const float* W = (const float*)d_in[2];
    const float* a_src = (const float*)d_in[3];
    const float* a_dst = (const float*)d_in[4];
    const float* conv_bias = (const float*)d_in[5];
    const float* bn_gamma = (const float*)d_in[6];
    const float* bn_beta = (const float*)d_in[7];
    const float* fc_w = (const float*)d_in[8];
    const float* fc_b = (const float*)d_in[9];
    const int* edge_index = (const int*)d_in[10];
    const int* batch = (const int*)d_in[11];
    float* out = (float*)d_out;

    char* ws = (char*)d_ws;
    size_t off = 0;
    auto alloc = [&](size_t bytes) {
        void* p = ws + off;
        off += (bytes + 255) & ~(size_t)255;
        return p;
    };
    float* bufP = (float*)alloc((size_t)N_NODES * 128 * 4);                    // layer output fp32
    unsigned short* h_bf = (unsigned short*)alloc((size_t)N_NODES * 128 * 2);  // h bf16
    unsigned short* Wt = (unsigned short*)alloc((size_t)L_LAYERS * 128 * 128 * 2);
    unsigned short* Wa = (unsigned short*)alloc((size_t)L_LAYERS * 16 * 128 * 2);
    float* als = (float*)alloc((size_t)N_NODES * 4 * 4);
    float* ald = (float*)alloc((size_t)N_NODES * 4 * 4);
    float* pooled = (float*)alloc((size_t)G_GRAPHS * HD * 4);
    int* fill = (int*)alloc((size_t)N_NODES * 4);
    int* csr = (int*)alloc((size_t)N_NODES * MAXDEG * 4);

    hipMemsetAsync(fill, 0, N_NODES * 4, stream);
    hipMemsetAsync(pooled, 0, G_GRAPHS * HD * 4, stream);
    const int NPREP = L_LAYERS * 128 * 128 + L_LAYERS * 16 * 128;
    prep_kernel<<<(NPREP + 255) / 256, 256, 0, stream>>>(W, a_src, a_dst, Wt, Wa);
    scatter_kernel<<<SC_BLOCKS, 256, 0, stream>>>(edge_index, fill, csr);

    const float* xcur = x_in;
    for (int l = 0; l < L_LAYERS; ++l) {
        gemm_mfma_kernel<<<(N_NODES + 63) / 64, 256, 0, stream>>>(
            xcur, Wt + (size_t)l * 128 * 128, Wa + (size_t)l * 16 * 128,
            h_bf, als, ald);
        agg_kernel<<<N_NODES / 4, 256, 0, stream>>>(
            h_bf, als, ald, fill, csr, conv_bias + l * 128, bufP);
        xcur = bufP;
    }

    int pool_waves = (N_NODES + POOL_CHUNK - 1) / POOL_CHUNK;
    pool_kernel<<<(pool_waves + 3) / 4, 256, 0, stream>>>(xcur, batch, pooled);
    bnfc_kernel<<<1, 256, 0, stream>>>(pooled, cond, bn_gamma, bn_beta, fc_w, fc_b, out);
}